// Round 3
// baseline (655.394 us; speedup 1.0000x reference)
//
#include <hip/hip_runtime.h>
#include <hip/hip_bf16.h>
#include <stdint.h>

#define TT 0.06f
#define PT 0.12f
#define EXPMAX 50.0f
#define SKEPS 1e-8f

typedef __attribute__((ext_vector_type(8))) short short8;
typedef __attribute__((ext_vector_type(4))) float f32x4;

static constexpr int B_ = 8, N_ = 1024, D_ = 768, K_ = 4096;
static constexpr int R_ROWS = B_ * N_;                    // 8192
static constexpr long LOGITS_ELEMS = (long)R_ROWS * K_;   // 33554432
static constexpr int KP = 3 * D_;                         // 2304 packed K

// ws offsets (bytes); logits live in d_out
static constexpr size_t OFF_APACK = 0;                                   // 8192*2304*2
static constexpr size_t OFF_BPACK = OFF_APACK + (size_t)R_ROWS * KP * 2; // 4096*2304*2
static constexpr size_t OFF_SHIFT = OFF_BPACK + (size_t)K_ * KP * 2;     // 32768*4
static constexpr size_t OFF_PMAX  = OFF_SHIFT + (size_t)B_ * K_ * 4;     // 8*8*4096*4
static constexpr size_t OFF_PSUM  = OFF_PMAX + (size_t)B_ * 8 * K_ * 4;
static constexpr size_t OFF_C     = OFF_PSUM + (size_t)B_ * 8 * K_ * 4;
static constexpr size_t OFF_R     = OFF_C + (size_t)B_ * K_ * 4;
static constexpr size_t OFF_LSE   = OFF_R + (size_t)R_ROWS * 4;
static constexpr size_t OFF_LOSSP = OFF_LSE + (size_t)R_ROWS * 4;

__device__ __forceinline__ float waveReduceSum(float v) {
#pragma unroll
    for (int m = 1; m < 64; m <<= 1) v += __shfl_xor(v, m, 64);
    return v;
}
__device__ __forceinline__ float waveReduceMax(float v) {
#pragma unroll
    for (int m = 1; m < 64; m <<= 1) v = fmaxf(v, __shfl_xor(v, m, 64));
    return v;
}

// ---- pack x: normalize rows, split to bf16 hi/lo, layout [hi | hi | lo] ----
__global__ __launch_bounds__(256) void k_pack_x(const float* __restrict__ x,
                                                __hip_bfloat16* __restrict__ Ap) {
    int r = blockIdx.x;
    const float* xr = x + (size_t)r * D_;
    int t = threadIdx.x;
    float v0 = xr[t], v1 = xr[t + 256], v2 = xr[t + 512];
    float ss = v0 * v0 + v1 * v1 + v2 * v2;
    ss = waveReduceSum(ss);
    __shared__ float sb[4];
    __shared__ float sscale;
    if ((t & 63) == 0) sb[t >> 6] = ss;
    __syncthreads();
    if (t == 0) {
        float s = sb[0] + sb[1] + sb[2] + sb[3];
        sscale = 1.0f / fmaxf(sqrtf(s), 1e-7f);
    }
    __syncthreads();
    float sc = sscale;
    __hip_bfloat16* ar = Ap + (size_t)r * KP;
    float vv[3] = {v0, v1, v2};
#pragma unroll
    for (int i = 0; i < 3; i++) {
        int d = t + i * 256;
        float xn = vv[i] * sc;
        __hip_bfloat16 hi = __float2bfloat16(xn);
        float lo = xn - __bfloat162float(hi);
        ar[d] = hi;
        ar[768 + d] = hi;
        ar[1536 + d] = __float2bfloat16(lo);
    }
}

// ---- pack W: split to bf16 hi/lo, layout [hi | lo | hi] ----
__global__ __launch_bounds__(256) void k_pack_w(const float* __restrict__ Wg,
                                                __hip_bfloat16* __restrict__ Bp) {
    int kk = blockIdx.x;
    const float* wr = Wg + (size_t)kk * D_;
    __hip_bfloat16* br = Bp + (size_t)kk * KP;
    int t = threadIdx.x;
#pragma unroll
    for (int i = 0; i < 3; i++) {
        int d = t + i * 256;
        float v = wr[d];
        __hip_bfloat16 hi = __float2bfloat16(v);
        float lo = v - __bfloat162float(hi);
        br[d] = hi;
        br[768 + d] = __float2bfloat16(lo);
        br[1536 + d] = hi;
    }
}

__global__ void k_init(float* C, float* R) {
    int i = blockIdx.x * 256 + threadIdx.x;
    if (i < B_ * K_) C[i] = 1.0f;
    if (i < R_ROWS) R[i] = 1.0f;
}

// ---- GEMM: logits[8192][4096] = Ap[8192][2304] * Bp[4096][2304]^T + bias ----
__global__ __launch_bounds__(256) void k_gemm(const __hip_bfloat16* __restrict__ Ap,
                                              const __hip_bfloat16* __restrict__ Bp,
                                              const float* __restrict__ bias,
                                              float* __restrict__ Lg) {
    __shared__ __align__(16) __hip_bfloat16 smA[128 * 32];
    __shared__ __align__(16) __hip_bfloat16 smB[128 * 32];
    int t = threadIdx.x;
    int lane = t & 63, w = t >> 6;
    int bn = blockIdx.x, bm = blockIdx.y;
    int wr = (w >> 1) * 64, wc = (w & 1) * 64;
    f32x4 acc[4][4];
#pragma unroll
    for (int i = 0; i < 4; i++)
#pragma unroll
        for (int j = 0; j < 4; j++) acc[i][j] = (f32x4){0.f, 0.f, 0.f, 0.f};

    int m0 = t >> 2, kof = (t & 3) * 8;  // chunk t covers rows 0..63, chunk t+256 rows 64..127
    const __hip_bfloat16* agb = Ap + (size_t)(bm * 128) * KP;
    const __hip_bfloat16* bgb = Bp + (size_t)(bn * 128) * KP;

    int arow = wr + (lane & 15);
    int brow = wc + (lane & 15);
    int kfr = (lane >> 4) * 8;

    for (int kt = 0; kt < KP / 32; ++kt) {
        int kb = kt * 32;
        *(short8*)(smA + m0 * 32 + kof) = *(const short8*)(agb + (size_t)m0 * KP + kb + kof);
        *(short8*)(smA + (m0 + 64) * 32 + kof) = *(const short8*)(agb + (size_t)(m0 + 64) * KP + kb + kof);
        *(short8*)(smB + m0 * 32 + kof) = *(const short8*)(bgb + (size_t)m0 * KP + kb + kof);
        *(short8*)(smB + (m0 + 64) * 32 + kof) = *(const short8*)(bgb + (size_t)(m0 + 64) * KP + kb + kof);
        __syncthreads();
        short8 af[4], bf[4];
#pragma unroll
        for (int i = 0; i < 4; i++) af[i] = *(const short8*)(smA + (arow + i * 16) * 32 + kfr);
#pragma unroll
        for (int j = 0; j < 4; j++) bf[j] = *(const short8*)(smB + (brow + j * 16) * 32 + kfr);
#pragma unroll
        for (int i = 0; i < 4; i++)
#pragma unroll
            for (int j = 0; j < 4; j++)
                acc[i][j] = __builtin_amdgcn_mfma_f32_16x16x32_bf16(af[i], bf[j], acc[i][j], 0, 0, 0);
        __syncthreads();
    }
    int colbase = bn * 128 + wc + (lane & 15);
    int rowbase = bm * 128 + wr + (lane >> 4) * 4;
#pragma unroll
    for (int j = 0; j < 4; j++) {
        int col = colbase + j * 16;
        float bb = bias[col];
#pragma unroll
        for (int i = 0; i < 4; i++) {
            int row = rowbase + i * 16;
#pragma unroll
            for (int rr = 0; rr < 4; rr++) {
                Lg[(size_t)(row + rr) * K_ + col] = acc[i][j][rr] + bb;
            }
        }
    }
}

// ---- column max partials over n (per batch) ----
__global__ __launch_bounds__(256) void k_colmax(const float* __restrict__ Lg, float* __restrict__ pmax) {
    int b = blockIdx.z, nc = blockIdx.y;
    int k = blockIdx.x * 256 + threadIdx.x;
    const float* base = Lg + (size_t)(b * N_ + nc * 128) * K_ + k;
    float m = -3.4e38f;
#pragma unroll 4
    for (int n = 0; n < 128; n++) m = fmaxf(m, base[(size_t)n * K_]);
    pmax[(size_t)(b * 8 + nc) * K_ + k] = m;
}

__global__ void k_shift(const float* __restrict__ pmax, float* __restrict__ shift) {
    int i = blockIdx.x * 256 + threadIdx.x;  // i = b*4096 + k
    int b = i >> 12, k = i & 4095;
    float m = -3.4e38f;
#pragma unroll
    for (int nc = 0; nc < 8; nc++) m = fmaxf(m, pmax[(size_t)(b * 8 + nc) * K_ + k]);
    shift[i] = m * (1.0f / TT);
}

// ---- sinkhorn column pass: psum[b][nc][k] = sum_n R_n * exp(L/T + 50 - shift_k) ----
__global__ __launch_bounds__(256) void k_colpass(const float* __restrict__ Lg,
                                                 const float* __restrict__ shift,
                                                 const float* __restrict__ R,
                                                 float* __restrict__ psum) {
    int b = blockIdx.z, nc = blockIdx.y;
    int k = blockIdx.x * 256 + threadIdx.x;
    float sh = EXPMAX - shift[b * K_ + k];
    const float* base = Lg + (size_t)(b * N_ + nc * 128) * K_ + k;
    const float* Rb = R + b * N_ + nc * 128;
    float s = 0.f;
#pragma unroll 4
    for (int n = 0; n < 128; n++) {
        float e = __expf(base[(size_t)n * K_] * (1.0f / TT) + sh);
        s += Rb[n] * e;
    }
    psum[(size_t)(b * 8 + nc) * K_ + k] = s;
}

__global__ void k_updC(const float* __restrict__ psum, float* __restrict__ C) {
    int i = blockIdx.x * 256 + threadIdx.x;  // b*4096 + k
    int b = i >> 12, k = i & 4095;
    float s = 0.f;
#pragma unroll
    for (int nc = 0; nc < 8; nc++) s += psum[(size_t)(b * 8 + nc) * K_ + k];
    float c = C[i];
    C[i] = c / (c * s + SKEPS);
}

// ---- sinkhorn row pass: S'_r = sum_k exp(...)*C_k ; R_r <- R_r/(R_r*S' + eps) ----
__global__ __launch_bounds__(256) void k_rowpass(const float* __restrict__ Lg,
                                                 const float* __restrict__ shift,
                                                 const float* __restrict__ C,
                                                 float* __restrict__ R) {
    int r = blockIdx.x;
    int b = r >> 10;
    const float* row = Lg + (size_t)r * K_;
    const float* shb = shift + b * K_;
    const float* Cb = C + b * K_;
    int t = threadIdx.x;
    float s = 0.f;
#pragma unroll
    for (int i = 0; i < 16; i++) {
        int k = t + i * 256;
        float e = __expf(row[k] * (1.0f / TT) + EXPMAX - shb[k]);
        s += e * Cb[k];
    }
    s = waveReduceSum(s);
    __shared__ float sb[4];
    if ((t & 63) == 0) sb[t >> 6] = s;
    __syncthreads();
    if (t == 0) {
        float tot = sb[0] + sb[1] + sb[2] + sb[3];
        float rv = R[r];
        R[r] = rv / (rv * tot + SKEPS);
    }
}

// ---- per-row logsumexp of pred = L/PT ----
__global__ __launch_bounds__(256) void k_rowlse(const float* __restrict__ Lg, float* __restrict__ lse) {
    int r = blockIdx.x;
    const float* row = Lg + (size_t)r * K_;
    int t = threadIdx.x;
    float vals[16];
    float m = -3.4e38f;
#pragma unroll
    for (int i = 0; i < 16; i++) {
        vals[i] = row[t + i * 256] * (1.0f / PT);
        m = fmaxf(m, vals[i]);
    }
    m = waveReduceMax(m);
    __shared__ float sb[4];
    __shared__ float smax;
    if ((t & 63) == 0) sb[t >> 6] = m;
    __syncthreads();
    if (t == 0) smax = fmaxf(fmaxf(sb[0], sb[1]), fmaxf(sb[2], sb[3]));
    __syncthreads();
    float mm = smax;
    float s = 0.f;
#pragma unroll
    for (int i = 0; i < 16; i++) s += __expf(vals[i] - mm);
    s = waveReduceSum(s);
    __shared__ float sb2[4];
    if ((t & 63) == 0) sb2[t >> 6] = s;
    __syncthreads();
    if (t == 0) lse[r] = mm + logf(sb2[0] + sb2[1] + sb2[2] + sb2[3]);
}

// ---- final: overwrite logits (in d_out) with assignments, accumulate loss partials ----
__global__ __launch_bounds__(256) void k_final(float* LgOut,
                                               const float* __restrict__ shift,
                                               const float* __restrict__ C,
                                               const float* __restrict__ R,
                                               const float* __restrict__ lse,
                                               float* __restrict__ lossp) {
    int r = blockIdx.x;
    int b = r >> 10;
    float* row = LgOut + (size_t)r * K_;
    const float* shb = shift + b * K_;
    const float* Cb = C + b * K_;
    float rv = R[r];
    float lz = lse[r];
    int t = threadIdx.x;
    float part = 0.f;
#pragma unroll
    for (int i = 0; i < 16; i++) {
        int k = t + i * 256;
        float lg = row[k];
        float e = __expf(lg * (1.0f / TT) + EXPMAX - shb[k]);
        float a = rv * e * Cb[k];
        row[k] = a;
        part += a * (lg * (1.0f / PT) - lz);
    }
    part = waveReduceSum(part);
    __shared__ float sb[4];
    if ((t & 63) == 0) sb[t >> 6] = part;
    __syncthreads();
    if (t == 0) lossp[r] = sb[0] + sb[1] + sb[2] + sb[3];
}

__global__ void k_loss(const float* __restrict__ lossp, float* __restrict__ out) {
    int t = threadIdx.x;
    double s = 0.0;
    for (int i = t; i < R_ROWS; i += 256) s += (double)lossp[i];
#pragma unroll
    for (int m = 1; m < 64; m <<= 1) s += __shfl_xor(s, m, 64);
    __shared__ double sb[4];
    if ((t & 63) == 0) sb[t >> 6] = s;
    __syncthreads();
    if (t == 0) out[LOGITS_ELEMS] = (float)(-(sb[0] + sb[1] + sb[2] + sb[3]) / (double)R_ROWS);
}

extern "C" void kernel_launch(void* const* d_in, const int* in_sizes, int n_in,
                              void* d_out, int out_size, void* d_ws, size_t ws_size,
                              hipStream_t stream) {
    const float* x = (const float*)d_in[0];
    const float* W = (const float*)d_in[1];
    const float* bias = (const float*)d_in[2];
    char* ws = (char*)d_ws;
    __hip_bfloat16* Ap = (__hip_bfloat16*)(ws + OFF_APACK);
    __hip_bfloat16* Bp = (__hip_bfloat16*)(ws + OFF_BPACK);
    float* shift = (float*)(ws + OFF_SHIFT);
    float* pmax = (float*)(ws + OFF_PMAX);
    float* psum = (float*)(ws + OFF_PSUM);
    float* C = (float*)(ws + OFF_C);
    float* R = (float*)(ws + OFF_R);
    float* lse = (float*)(ws + OFF_LSE);
    float* lossp = (float*)(ws + OFF_LOSSP);
    float* out = (float*)d_out;
    float* Lg = out;  // logits live in d_out; final pass overwrites in place

    k_pack_x<<<dim3(R_ROWS), dim3(256), 0, stream>>>(x, Ap);
    k_pack_w<<<dim3(K_), dim3(256), 0, stream>>>(W, Bp);
    k_init<<<dim3(128), dim3(256), 0, stream>>>(C, R);
    k_gemm<<<dim3(K_ / 128, R_ROWS / 128), dim3(256), 0, stream>>>(Ap, Bp, bias, Lg);
    k_colmax<<<dim3(16, 8, 8), dim3(256), 0, stream>>>(Lg, pmax);
    k_shift<<<dim3(128), dim3(256), 0, stream>>>(pmax, shift);
    for (int it = 0; it < 3; ++it) {
        k_colpass<<<dim3(16, 8, 8), dim3(256), 0, stream>>>(Lg, shift, R, psum);
        k_updC<<<dim3(128), dim3(256), 0, stream>>>(psum, C);
        k_rowpass<<<dim3(R_ROWS), dim3(256), 0, stream>>>(Lg, shift, C, R);
    }
    k_rowlse<<<dim3(R_ROWS), dim3(256), 0, stream>>>(Lg, lse);
    k_final<<<dim3(R_ROWS), dim3(256), 0, stream>>>(Lg, shift, C, R, lse, lossp);
    k_loss<<<dim3(1), dim3(256), 0, stream>>>(lossp, out);
}

// Round 5
// 566.284 us; speedup vs baseline: 1.1574x; 1.1574x over previous
//
#include <hip/hip_runtime.h>
#include <hip/hip_bf16.h>
#include <stdint.h>

#define TT 0.06f
#define PT 0.12f
#define EXPMAX 50.0f
#define SKEPS 1e-8f

typedef __attribute__((ext_vector_type(8))) short short8;
typedef __attribute__((ext_vector_type(4))) float f32x4;

static constexpr int B_ = 8, N_ = 1024, D_ = 768, K_ = 4096;
static constexpr int R_ROWS = B_ * N_;                    // 8192
static constexpr long LOGITS_ELEMS = (long)R_ROWS * K_;   // 33554432
static constexpr int KP = 3 * D_;                         // 2304 packed K

// ws offsets (bytes); logits live in d_out
static constexpr size_t OFF_APACK = 0;                                   // 8192*2304*2
static constexpr size_t OFF_BPACK = OFF_APACK + (size_t)R_ROWS * KP * 2; // 4096*2304*2
static constexpr size_t OFF_SHIFT = OFF_BPACK + (size_t)K_ * KP * 2;     // 32768*4
static constexpr size_t OFF_PMAX  = OFF_SHIFT + (size_t)B_ * K_ * 4;     // 64*4096*4
static constexpr size_t OFF_PSUM  = OFF_PMAX + (size_t)64 * K_ * 4;
static constexpr size_t OFF_C     = OFF_PSUM + (size_t)B_ * 8 * K_ * 4;
static constexpr size_t OFF_R     = OFF_C + (size_t)B_ * K_ * 4;
static constexpr size_t OFF_LSE   = OFF_R + (size_t)R_ROWS * 4;
static constexpr size_t OFF_LOSSP = OFF_LSE + (size_t)R_ROWS * 4;

__device__ __forceinline__ float waveReduceSum(float v) {
#pragma unroll
    for (int m = 1; m < 64; m <<= 1) v += __shfl_xor(v, m, 64);
    return v;
}
__device__ __forceinline__ float waveReduceMax(float v) {
#pragma unroll
    for (int m = 1; m < 64; m <<= 1) v = fmaxf(v, __shfl_xor(v, m, 64));
    return v;
}

// async global->LDS, 16B per lane; LDS dest = wave-uniform base + lane*16
__device__ __forceinline__ void gload_lds16(const __hip_bfloat16* g, __hip_bfloat16* l) {
    __builtin_amdgcn_global_load_lds((const __attribute__((address_space(1))) void*)g,
                                     (__attribute__((address_space(3))) void*)l, 16, 0, 0);
}

// ---- pack x: normalize rows, split to bf16 hi/lo, layout [hi | hi | lo] ----
__global__ __launch_bounds__(256) void k_pack_x(const float* __restrict__ x,
                                                __hip_bfloat16* __restrict__ Ap) {
    int r = blockIdx.x;
    const float* xr = x + (size_t)r * D_;
    int t = threadIdx.x;
    float v0 = xr[t], v1 = xr[t + 256], v2 = xr[t + 512];
    float ss = v0 * v0 + v1 * v1 + v2 * v2;
    ss = waveReduceSum(ss);
    __shared__ float sb[4];
    __shared__ float sscale;
    if ((t & 63) == 0) sb[t >> 6] = ss;
    __syncthreads();
    if (t == 0) {
        float s = sb[0] + sb[1] + sb[2] + sb[3];
        sscale = 1.0f / fmaxf(sqrtf(s), 1e-7f);
    }
    __syncthreads();
    float sc = sscale;
    __hip_bfloat16* ar = Ap + (size_t)r * KP;
    float vv[3] = {v0, v1, v2};
#pragma unroll
    for (int i = 0; i < 3; i++) {
        int d = t + i * 256;
        float xn = vv[i] * sc;
        __hip_bfloat16 hi = __float2bfloat16(xn);
        float lo = xn - __bfloat162float(hi);
        ar[d] = hi;
        ar[768 + d] = hi;
        ar[1536 + d] = __float2bfloat16(lo);
    }
}

// ---- pack W: split to bf16 hi/lo, layout [hi | lo | hi] ----
__global__ __launch_bounds__(256) void k_pack_w(const float* __restrict__ Wg,
                                                __hip_bfloat16* __restrict__ Bp) {
    int kk = blockIdx.x;
    const float* wr = Wg + (size_t)kk * D_;
    __hip_bfloat16* br = Bp + (size_t)kk * KP;
    int t = threadIdx.x;
#pragma unroll
    for (int i = 0; i < 3; i++) {
        int d = t + i * 256;
        float v = wr[d];
        __hip_bfloat16 hi = __float2bfloat16(v);
        float lo = v - __bfloat162float(hi);
        br[d] = hi;
        br[768 + d] = __float2bfloat16(lo);
        br[1536 + d] = hi;
    }
}

__global__ void k_init(float* C, float* R) {
    int i = blockIdx.x * 256 + threadIdx.x;
    if (i < B_ * K_) C[i] = 1.0f;
    if (i < R_ROWS) R[i] = 1.0f;
}

// ---- GEMM: logits = Ap * Bp^T + bias; fused per-column block-max -> pmax ----
__global__ __launch_bounds__(256) void k_gemm(const __hip_bfloat16* __restrict__ Ap,
                                              const __hip_bfloat16* __restrict__ Bp,
                                              const float* __restrict__ bias,
                                              float* __restrict__ Lg,
                                              float* __restrict__ pmax) {
    __shared__ __align__(16) __hip_bfloat16 smA[128 * 32];
    __shared__ __align__(16) __hip_bfloat16 smB[128 * 32];
    __shared__ float sm_cmax[4][64];
    int t = threadIdx.x;
    int lane = t & 63, w = t >> 6;
    int bn = blockIdx.x, bm = blockIdx.y;
    int wr = (w >> 1) * 64, wc = (w & 1) * 64;
    f32x4 acc[4][4];
#pragma unroll
    for (int i = 0; i < 4; i++)
#pragma unroll
        for (int j = 0; j < 4; j++) acc[i][j] = (f32x4){0.f, 0.f, 0.f, 0.f};

    // staging addresses: wave w stages rows [w*16, w*16+16) and +64 of each tile.
    // lane l -> row base + (l>>2), col elems (l&3)*8  (matches linear LDS dest base+lane*16)
    const __hip_bfloat16* gA0 = Ap + (size_t)(bm * 128 + w * 16 + (lane >> 2)) * KP + (lane & 3) * 8;
    const __hip_bfloat16* gA1 = gA0 + (size_t)64 * KP;
    const __hip_bfloat16* gB0 = Bp + (size_t)(bn * 128 + w * 16 + (lane >> 2)) * KP + (lane & 3) * 8;
    const __hip_bfloat16* gB1 = gB0 + (size_t)64 * KP;
    __hip_bfloat16* lA0 = smA + w * 16 * 32;
    __hip_bfloat16* lA1 = smA + (64 + w * 16) * 32;
    __hip_bfloat16* lB0 = smB + w * 16 * 32;
    __hip_bfloat16* lB1 = smB + (64 + w * 16) * 32;

    int arow = wr + (lane & 15);
    int brow = wc + (lane & 15);
    int kfr = (lane >> 4) * 8;

    for (int kt = 0; kt < KP / 32; ++kt) {
        gload_lds16(gA0, lA0);
        gload_lds16(gA1, lA1);
        gload_lds16(gB0, lB0);
        gload_lds16(gB1, lB1);
        gA0 += 32; gA1 += 32; gB0 += 32; gB1 += 32;
        __syncthreads();  // drains vmcnt: LDS tiles ready
        short8 af[4], bf[4];
#pragma unroll
        for (int i = 0; i < 4; i++) af[i] = *(const short8*)(smA + (arow + i * 16) * 32 + kfr);
#pragma unroll
        for (int j = 0; j < 4; j++) bf[j] = *(const short8*)(smB + (brow + j * 16) * 32 + kfr);
#pragma unroll
        for (int i = 0; i < 4; i++)
#pragma unroll
            for (int j = 0; j < 4; j++)
                acc[i][j] = __builtin_amdgcn_mfma_f32_16x16x32_bf16(af[i], bf[j], acc[i][j], 0, 0, 0);
        __syncthreads();
    }
    // epilogue: write logits + per-column max over this block's 128 rows
    int colbase = bn * 128 + wc + (lane & 15);
    int rowbase = bm * 128 + wr + (lane >> 4) * 4;
#pragma unroll
    for (int j = 0; j < 4; j++) {
        int col = colbase + j * 16;
        float bb = bias[col];
        float mx = -3.4e38f;
#pragma unroll
        for (int i = 0; i < 4; i++) {
            int row = rowbase + i * 16;
#pragma unroll
            for (int rr = 0; rr < 4; rr++) {
                float v = acc[i][j][rr] + bb;
                Lg[(size_t)(row + rr) * K_ + col] = v;
                mx = fmaxf(mx, v);
            }
        }
        // reduce across the 4 row-groups (lane>>4) sharing this col
        mx = fmaxf(mx, __shfl_xor(mx, 16, 64));
        mx = fmaxf(mx, __shfl_xor(mx, 32, 64));
        if ((lane >> 4) == 0) sm_cmax[w][j * 16 + (lane & 15)] = mx;
    }
    __syncthreads();
    if (t < 128) {
        int half = t >> 6;  // 0: cols 0..63 (warps 0,2), 1: cols 64..127 (warps 1,3)
        int ci = t & 63;
        float m = fmaxf(sm_cmax[half][ci], sm_cmax[half + 2][ci]);
        pmax[(size_t)bm * K_ + bn * 128 + t] = m;
    }
}

__global__ void k_shift(const float* __restrict__ pmax, float* __restrict__ shift) {
    int i = blockIdx.x * 256 + threadIdx.x;  // i = b*4096 + k
    int b = i >> 12, k = i & 4095;
    float m = -3.4e38f;
#pragma unroll
    for (int nc = 0; nc < 8; nc++) m = fmaxf(m, pmax[(size_t)(b * 8 + nc) * K_ + k]);
    shift[i] = m * (1.0f / TT);
}

// ---- sinkhorn column pass: psum[b][nc][k] = sum_n R_n * exp(L/T + 50 - shift_k) ----
__global__ __launch_bounds__(256) void k_colpass(const float* __restrict__ Lg,
                                                 const float* __restrict__ shift,
                                                 const float* __restrict__ R,
                                                 float* __restrict__ psum) {
    int b = blockIdx.z, nc = blockIdx.y;
    int k = blockIdx.x * 256 + threadIdx.x;
    float sh = EXPMAX - shift[b * K_ + k];
    const float* base = Lg + (size_t)(b * N_ + nc * 128) * K_ + k;
    const float* Rb = R + b * N_ + nc * 128;
    float s = 0.f;
#pragma unroll 4
    for (int n = 0; n < 128; n++) {
        float e = __expf(base[(size_t)n * K_] * (1.0f / TT) + sh);
        s += Rb[n] * e;
    }
    psum[(size_t)(b * 8 + nc) * K_ + k] = s;
}

__global__ void k_updC(const float* __restrict__ psum, float* __restrict__ C) {
    int i = blockIdx.x * 256 + threadIdx.x;  // b*4096 + k
    int b = i >> 12, k = i & 4095;
    float s = 0.f;
#pragma unroll
    for (int nc = 0; nc < 8; nc++) s += psum[(size_t)(b * 8 + nc) * K_ + k];
    float c = C[i];
    C[i] = c / (c * s + SKEPS);
}

// ---- sinkhorn row pass: S'_r = sum_k exp(...)*C_k ; R_r <- R_r/(R_r*S' + eps) ----
__global__ __launch_bounds__(256) void k_rowpass(const float* __restrict__ Lg,
                                                 const float* __restrict__ shift,
                                                 const float* __restrict__ C,
                                                 float* __restrict__ R) {
    int r = blockIdx.x;
    int b = r >> 10;
    const float* row = Lg + (size_t)r * K_;
    const float* shb = shift + b * K_;
    const float* Cb = C + b * K_;
    int t = threadIdx.x;
    float s = 0.f;
#pragma unroll
    for (int i = 0; i < 16; i++) {
        int k = t + i * 256;
        float e = __expf(row[k] * (1.0f / TT) + EXPMAX - shb[k]);
        s += e * Cb[k];
    }
    s = waveReduceSum(s);
    __shared__ float sb[4];
    if ((t & 63) == 0) sb[t >> 6] = s;
    __syncthreads();
    if (t == 0) {
        float tot = sb[0] + sb[1] + sb[2] + sb[3];
        float rv = R[r];
        R[r] = rv / (rv * tot + SKEPS);
    }
}

// ---- first rowpass, fused with per-row logsumexp of pred = L/PT ----
__global__ __launch_bounds__(256) void k_rowpass_lse(const float* __restrict__ Lg,
                                                     const float* __restrict__ shift,
                                                     const float* __restrict__ C,
                                                     float* __restrict__ R,
                                                     float* __restrict__ lse) {
    int r = blockIdx.x;
    int b = r >> 10;
    const float* row = Lg + (size_t)r * K_;
    const float* shb = shift + b * K_;
    const float* Cb = C + b * K_;
    int t = threadIdx.x;
    float vals[16];
    float s = 0.f, mx = -3.4e38f;
#pragma unroll
    for (int i = 0; i < 16; i++) {
        int k = t + i * 256;
        float v = row[k];
        vals[i] = v;
        s += __expf(v * (1.0f / TT) + EXPMAX - shb[k]) * Cb[k];
        mx = fmaxf(mx, v);
    }
    s = waveReduceSum(s);
    mx = waveReduceMax(mx);
    __shared__ float sbS[4], sbM[4];
    __shared__ float gS, gM;
    if ((t & 63) == 0) { sbS[t >> 6] = s; sbM[t >> 6] = mx; }
    __syncthreads();
    if (t == 0) {
        gS = sbS[0] + sbS[1] + sbS[2] + sbS[3];
        gM = fmaxf(fmaxf(sbM[0], sbM[1]), fmaxf(sbM[2], sbM[3]));
    }
    __syncthreads();
    float mm = gM * (1.0f / PT);
    float s2 = 0.f;
#pragma unroll
    for (int i = 0; i < 16; i++) s2 += __expf(vals[i] * (1.0f / PT) - mm);
    s2 = waveReduceSum(s2);
    __shared__ float sb2[4];
    if ((t & 63) == 0) sb2[t >> 6] = s2;
    __syncthreads();
    if (t == 0) {
        lse[r] = mm + logf(sb2[0] + sb2[1] + sb2[2] + sb2[3]);
        float rv = R[r];
        R[r] = rv / (rv * gS + SKEPS);
    }
}

// ---- final: overwrite logits (in d_out) with assignments, accumulate loss partials ----
__global__ __launch_bounds__(256) void k_final(float* LgOut,
                                               const float* __restrict__ shift,
                                               const float* __restrict__ C,
                                               const float* __restrict__ R,
                                               const float* __restrict__ lse,
                                               float* __restrict__ lossp) {
    int r = blockIdx.x;
    int b = r >> 10;
    float* row = LgOut + (size_t)r * K_;
    const float* shb = shift + b * K_;
    const float* Cb = C + b * K_;
    float rv = R[r];
    float lz = lse[r];
    int t = threadIdx.x;
    float part = 0.f;
#pragma unroll
    for (int i = 0; i < 16; i++) {
        int k = t + i * 256;
        float lg = row[k];
        float e = __expf(lg * (1.0f / TT) + EXPMAX - shb[k]);
        float a = rv * e * Cb[k];
        row[k] = a;
        part += a * (lg * (1.0f / PT) - lz);
    }
    part = waveReduceSum(part);
    __shared__ float sb[4];
    if ((t & 63) == 0) sb[t >> 6] = part;
    __syncthreads();
    if (t == 0) lossp[r] = sb[0] + sb[1] + sb[2] + sb[3];
}

__global__ void k_loss(const float* __restrict__ lossp, float* __restrict__ out) {
    int t = threadIdx.x;
    double s = 0.0;
    for (int i = t; i < R_ROWS; i += 256) s += (double)lossp[i];
#pragma unroll
    for (int m = 1; m < 64; m <<= 1) s += __shfl_xor(s, m, 64);
    __shared__ double sb[4];
    if ((t & 63) == 0) sb[t >> 6] = s;
    __syncthreads();
    if (t == 0) out[LOGITS_ELEMS] = (float)(-(sb[0] + sb[1] + sb[2] + sb[3]) / (double)R_ROWS);
}

extern "C" void kernel_launch(void* const* d_in, const int* in_sizes, int n_in,
                              void* d_out, int out_size, void* d_ws, size_t ws_size,
                              hipStream_t stream) {
    const float* x = (const float*)d_in[0];
    const float* W = (const float*)d_in[1];
    const float* bias = (const float*)d_in[2];
    char* ws = (char*)d_ws;
    __hip_bfloat16* Ap = (__hip_bfloat16*)(ws + OFF_APACK);
    __hip_bfloat16* Bp = (__hip_bfloat16*)(ws + OFF_BPACK);
    float* shift = (float*)(ws + OFF_SHIFT);
    float* pmax = (float*)(ws + OFF_PMAX);
    float* psum = (float*)(ws + OFF_PSUM);
    float* C = (float*)(ws + OFF_C);
    float* R = (float*)(ws + OFF_R);
    float* lse = (float*)(ws + OFF_LSE);
    float* lossp = (float*)(ws + OFF_LOSSP);
    float* out = (float*)d_out;
    float* Lg = out;  // logits live in d_out; final pass overwrites in place

    k_pack_x<<<dim3(R_ROWS), dim3(256), 0, stream>>>(x, Ap);
    k_pack_w<<<dim3(K_), dim3(256), 0, stream>>>(W, Bp);
    k_init<<<dim3(128), dim3(256), 0, stream>>>(C, R);
    k_gemm<<<dim3(K_ / 128, R_ROWS / 128), dim3(256), 0, stream>>>(Ap, Bp, bias, Lg, pmax);
    k_shift<<<dim3(128), dim3(256), 0, stream>>>(pmax, shift);
    // iteration 0 (rowpass fused with LSE)
    k_colpass<<<dim3(16, 8, 8), dim3(256), 0, stream>>>(Lg, shift, R, psum);
    k_updC<<<dim3(128), dim3(256), 0, stream>>>(psum, C);
    k_rowpass_lse<<<dim3(R_ROWS), dim3(256), 0, stream>>>(Lg, shift, C, R, lse);
    // iterations 1,2
    for (int it = 1; it < 3; ++it) {
        k_colpass<<<dim3(16, 8, 8), dim3(256), 0, stream>>>(Lg, shift, R, psum);
        k_updC<<<dim3(128), dim3(256), 0, stream>>>(psum, C);
        k_rowpass<<<dim3(R_ROWS), dim3(256), 0, stream>>>(Lg, shift, C, R);
    }
    k_final<<<dim3(R_ROWS), dim3(256), 0, stream>>>(Lg, shift, C, R, lse, lossp);
    k_loss<<<dim3(1), dim3(256), 0, stream>>>(lossp, out);
}

// Round 6
// 466.348 us; speedup vs baseline: 1.4054x; 1.2143x over previous
//
#include <hip/hip_runtime.h>
#include <hip/hip_bf16.h>
#include <stdint.h>

#define TT 0.06f
#define PT 0.12f
#define EXPMAX 50.0f
#define SKEPS 1e-8f

typedef __attribute__((ext_vector_type(8))) short short8;
typedef __attribute__((ext_vector_type(4))) float f32x4;

static constexpr int B_ = 8, N_ = 1024, D_ = 768, K_ = 4096;
static constexpr int R_ROWS = B_ * N_;                    // 8192
static constexpr long LOGITS_ELEMS = (long)R_ROWS * K_;   // 33554432
static constexpr int KP = 3 * D_;                         // 2304 packed K
static constexpr int CH_ROWS = 16;                        // rows per chunk in fused passes
static constexpr int NCHUNK = R_ROWS / CH_ROWS;           // 512

// ws layout (bytes). psum aliases BPACK (Bp dead after GEMM).
static constexpr size_t OFF_APACK = 0;                                    // 37,748,736
static constexpr size_t OFF_BPACK = OFF_APACK + (size_t)R_ROWS * KP * 2;  // +18,874,368
static constexpr size_t OFF_PSUM  = OFF_BPACK;                            // 512*4096*4 = 8 MB (alias)
static constexpr size_t OFF_PMAX  = OFF_BPACK + (size_t)K_ * KP * 2;      // 64*4096*4 = 1 MB
static constexpr size_t OFF_PSUM0 = OFF_PMAX + (size_t)64 * K_ * 4;       // 1 MB
static constexpr size_t OFF_D     = OFF_PSUM0 + (size_t)64 * K_ * 4;      // 8*4096*4
static constexpr size_t OFF_C     = OFF_D + (size_t)B_ * K_ * 4;          // 8*4096*4
static constexpr size_t OFF_R     = OFF_C + (size_t)B_ * K_ * 4;          // 8192*4
static constexpr size_t OFF_LSE   = OFF_R + (size_t)R_ROWS * 4;           // 8192*4
static constexpr size_t OFF_LOSSP = OFF_LSE + (size_t)R_ROWS * 4;         // 512*4

__device__ __forceinline__ float waveReduceSum(float v) {
#pragma unroll
    for (int m = 1; m < 64; m <<= 1) v += __shfl_xor(v, m, 64);
    return v;
}
__device__ __forceinline__ float waveReduceMax(float v) {
#pragma unroll
    for (int m = 1; m < 64; m <<= 1) v = fmaxf(v, __shfl_xor(v, m, 64));
    return v;
}

// async global->LDS, 16B per lane; LDS dest = wave-uniform base + lane*16
__device__ __forceinline__ void gload_lds16(const __hip_bfloat16* g, __hip_bfloat16* l) {
    __builtin_amdgcn_global_load_lds((const __attribute__((address_space(1))) void*)g,
                                     (__attribute__((address_space(3))) void*)l, 16, 0, 0);
}

// ---- pack x: normalize rows, split to bf16 hi/lo, layout [hi | hi | lo] ----
__global__ __launch_bounds__(256) void k_pack_x(const float* __restrict__ x,
                                                __hip_bfloat16* __restrict__ Ap) {
    int r = blockIdx.x;
    const float* xr = x + (size_t)r * D_;
    int t = threadIdx.x;
    float v0 = xr[t], v1 = xr[t + 256], v2 = xr[t + 512];
    float ss = v0 * v0 + v1 * v1 + v2 * v2;
    ss = waveReduceSum(ss);
    __shared__ float sb[4];
    __shared__ float sscale;
    if ((t & 63) == 0) sb[t >> 6] = ss;
    __syncthreads();
    if (t == 0) {
        float s = sb[0] + sb[1] + sb[2] + sb[3];
        sscale = 1.0f / fmaxf(sqrtf(s), 1e-7f);
    }
    __syncthreads();
    float sc = sscale;
    __hip_bfloat16* ar = Ap + (size_t)r * KP;
    float vv[3] = {v0, v1, v2};
#pragma unroll
    for (int i = 0; i < 3; i++) {
        int d = t + i * 256;
        float xn = vv[i] * sc;
        __hip_bfloat16 hi = __float2bfloat16(xn);
        float lo = xn - __bfloat162float(hi);
        ar[d] = hi;
        ar[768 + d] = hi;
        ar[1536 + d] = __float2bfloat16(lo);
    }
}

// ---- pack W: split to bf16 hi/lo, layout [hi | lo | hi] ----
__global__ __launch_bounds__(256) void k_pack_w(const float* __restrict__ Wg,
                                                __hip_bfloat16* __restrict__ Bp) {
    int kk = blockIdx.x;
    const float* wr = Wg + (size_t)kk * D_;
    __hip_bfloat16* br = Bp + (size_t)kk * KP;
    int t = threadIdx.x;
#pragma unroll
    for (int i = 0; i < 3; i++) {
        int d = t + i * 256;
        float v = wr[d];
        __hip_bfloat16 hi = __float2bfloat16(v);
        float lo = v - __bfloat162float(hi);
        br[d] = hi;
        br[768 + d] = __float2bfloat16(lo);
        br[1536 + d] = hi;
    }
}

// ---- GEMM: logits = Ap * Bp^T + bias; fused col-max AND col-exp-sum partials ----
__global__ __launch_bounds__(256) void k_gemm(const __hip_bfloat16* __restrict__ Ap,
                                              const __hip_bfloat16* __restrict__ Bp,
                                              const float* __restrict__ bias,
                                              float* __restrict__ Lg,
                                              float* __restrict__ pmax,
                                              float* __restrict__ psum0) {
    __shared__ __align__(16) __hip_bfloat16 smA[128 * 32];
    __shared__ __align__(16) __hip_bfloat16 smB[128 * 32];
    __shared__ float sm_cmax[4][64];
    __shared__ float sm_csum[4][64];
    __shared__ float sm_bmax[128];
    int t = threadIdx.x;
    int lane = t & 63, w = t >> 6;
    int bn = blockIdx.x, bm = blockIdx.y;
    int wr = (w >> 1) * 64, wc = (w & 1) * 64;
    f32x4 acc[4][4];
#pragma unroll
    for (int i = 0; i < 4; i++)
#pragma unroll
        for (int j = 0; j < 4; j++) acc[i][j] = (f32x4){0.f, 0.f, 0.f, 0.f};

    const __hip_bfloat16* gA0 = Ap + (size_t)(bm * 128 + w * 16 + (lane >> 2)) * KP + (lane & 3) * 8;
    const __hip_bfloat16* gA1 = gA0 + (size_t)64 * KP;
    const __hip_bfloat16* gB0 = Bp + (size_t)(bn * 128 + w * 16 + (lane >> 2)) * KP + (lane & 3) * 8;
    const __hip_bfloat16* gB1 = gB0 + (size_t)64 * KP;
    __hip_bfloat16* lA0 = smA + w * 16 * 32;
    __hip_bfloat16* lA1 = smA + (64 + w * 16) * 32;
    __hip_bfloat16* lB0 = smB + w * 16 * 32;
    __hip_bfloat16* lB1 = smB + (64 + w * 16) * 32;

    int arow = wr + (lane & 15);
    int brow = wc + (lane & 15);
    int kfr = (lane >> 4) * 8;

    for (int kt = 0; kt < KP / 32; ++kt) {
        gload_lds16(gA0, lA0);
        gload_lds16(gA1, lA1);
        gload_lds16(gB0, lB0);
        gload_lds16(gB1, lB1);
        gA0 += 32; gA1 += 32; gB0 += 32; gB1 += 32;
        __syncthreads();
        short8 af[4], bf[4];
#pragma unroll
        for (int i = 0; i < 4; i++) af[i] = *(const short8*)(smA + (arow + i * 16) * 32 + kfr);
#pragma unroll
        for (int j = 0; j < 4; j++) bf[j] = *(const short8*)(smB + (brow + j * 16) * 32 + kfr);
#pragma unroll
        for (int i = 0; i < 4; i++)
#pragma unroll
            for (int j = 0; j < 4; j++)
                acc[i][j] = __builtin_amdgcn_mfma_f32_16x16x32_bf16(af[i], bf[j], acc[i][j], 0, 0, 0);
        __syncthreads();
    }
    // epilogue phase 1: write logits + per-warp col max
    int colbase = bn * 128 + wc + (lane & 15);
    int rowbase = bm * 128 + wr + (lane >> 4) * 4;
    float bbv[4];
#pragma unroll
    for (int j = 0; j < 4; j++) {
        int col = colbase + j * 16;
        float bb = bias[col];
        bbv[j] = bb;
        float mx = -3.4e38f;
#pragma unroll
        for (int i = 0; i < 4; i++) {
            int row = rowbase + i * 16;
#pragma unroll
            for (int rr = 0; rr < 4; rr++) {
                float v = acc[i][j][rr] + bb;
                Lg[(size_t)(row + rr) * K_ + col] = v;
                mx = fmaxf(mx, v);
            }
        }
        mx = fmaxf(mx, __shfl_xor(mx, 16, 64));
        mx = fmaxf(mx, __shfl_xor(mx, 32, 64));
        if ((lane >> 4) == 0) sm_cmax[w][j * 16 + (lane & 15)] = mx;
    }
    __syncthreads();
    // combine warp-pairs -> block col max; publish to all + pmax
    if (t < 128) {
        int half = t >> 6, ci = t & 63;
        float m = fmaxf(sm_cmax[half][ci], sm_cmax[half + 2][ci]);
        sm_bmax[t] = m;
        pmax[(size_t)bm * K_ + bn * 128 + t] = m;
    }
    __syncthreads();
    // epilogue phase 2: per-block col sums of exp((v - M)/TT)
#pragma unroll
    for (int j = 0; j < 4; j++) {
        int bcol = (w & 1) * 64 + j * 16 + (lane & 15);
        float M = sm_bmax[bcol];
        float s = 0.f;
#pragma unroll
        for (int i = 0; i < 4; i++)
#pragma unroll
            for (int rr = 0; rr < 4; rr++)
                s += __expf((acc[i][j][rr] + bbv[j] - M) * (1.0f / TT));
        s += __shfl_xor(s, 16, 64);
        s += __shfl_xor(s, 32, 64);
        if ((lane >> 4) == 0) sm_csum[w][j * 16 + (lane & 15)] = s;
    }
    __syncthreads();
    if (t < 128) {
        int half = t >> 6, ci = t & 63;
        psum0[(size_t)bm * K_ + bn * 128 + t] = sm_csum[half][ci] + sm_csum[half + 2][ci];
    }
}

// ---- prep: per (b,k): D = 50 - colmax/TT ; S0 = sum_chunks P*exp(m/TT + D) ; C0 = 1/(S0+eps) ----
__global__ __launch_bounds__(256) void k_prep(const float* __restrict__ pmax,
                                              const float* __restrict__ psum0,
                                              float* __restrict__ Dv,
                                              float* __restrict__ Cc) {
    int i = blockIdx.x * 256 + threadIdx.x;  // b*4096 + k
    int b = i >> 12, k = i & 4095;
    float mv[8];
    float m = -3.4e38f;
#pragma unroll
    for (int nc = 0; nc < 8; nc++) {
        mv[nc] = pmax[(size_t)(b * 8 + nc) * K_ + k];
        m = fmaxf(m, mv[nc]);
    }
    float Dd = EXPMAX - m * (1.0f / TT);
    float S0 = 0.f;
#pragma unroll
    for (int nc = 0; nc < 8; nc++)
        S0 += psum0[(size_t)(b * 8 + nc) * K_ + k] * __expf(mv[nc] * (1.0f / TT) + Dd);
    Dv[i] = Dd;
    Cc[i] = 1.0f / (S0 + SKEPS);
}

// ---- fused pass: per row: T = sum e*C -> R_new ; accumulate R_new*e into col partials.
// FIRST: R_prev = 1 and also computes row LSE of L/PT. ----
template <bool FIRST>
__global__ __launch_bounds__(512) void k_pass(const float* __restrict__ Lg,
                                              const float* __restrict__ Dv,
                                              const float* __restrict__ Cc,
                                              float* __restrict__ Rv,
                                              float* __restrict__ psum,
                                              float* __restrict__ lse) {
    int chunk = blockIdx.x;  // 0..511
    int b = chunk >> 6;
    int t = threadIdx.x;
    int k0 = t * 8;
    const float* Db = Dv + (size_t)b * K_ + k0;
    const float* Cb = Cc + (size_t)b * K_ + k0;
    float Dr[8], Cr[8], acc[8];
#pragma unroll
    for (int j = 0; j < 8; j++) { Dr[j] = Db[j]; Cr[j] = Cb[j]; acc[j] = 0.f; }
    __shared__ float sbS[2][8], sbM[2][8], sb2[2][8];
    int wv = t >> 6;
    for (int rr = 0; rr < CH_ROWS; ++rr) {
        int r = chunk * CH_ROWS + rr;
        const float* row = Lg + (size_t)r * K_;
        f32x4 La = *(const f32x4*)(row + k0);
        f32x4 Lb = *(const f32x4*)(row + k0 + 4);
        float Lv[8] = {La[0], La[1], La[2], La[3], Lb[0], Lb[1], Lb[2], Lb[3]};
        float e[8];
        float dotp = 0.f, mxl = -3.4e38f;
#pragma unroll
        for (int j = 0; j < 8; j++) {
            e[j] = __expf(Lv[j] * (1.0f / TT) + Dr[j]);
            dotp += e[j] * Cr[j];
            if (FIRST) mxl = fmaxf(mxl, Lv[j]);
        }
        dotp = waveReduceSum(dotp);
        if (FIRST) mxl = waveReduceMax(mxl);
        int par = rr & 1;
        if ((t & 63) == 0) {
            sbS[par][wv] = dotp;
            if (FIRST) sbM[par][wv] = mxl;
        }
        __syncthreads();
        float T = 0.f, MX = -3.4e38f;
#pragma unroll
        for (int q = 0; q < 8; q++) {
            T += sbS[par][q];
            if (FIRST) MX = fmaxf(MX, sbM[par][q]);
        }
        float Rprev = FIRST ? 1.0f : Rv[r];
        float Rnew = Rprev / (Rprev * T + SKEPS);
#pragma unroll
        for (int j = 0; j < 8; j++) acc[j] += Rnew * e[j];
        if (t == 0) Rv[r] = Rnew;
        if (FIRST) {
            float mm = MX * (1.0f / PT);
            float s2 = 0.f;
#pragma unroll
            for (int j = 0; j < 8; j++) s2 += __expf(Lv[j] * (1.0f / PT) - mm);
            s2 = waveReduceSum(s2);
            if ((t & 63) == 0) sb2[par][wv] = s2;
            __syncthreads();
            if (t == 0) {
                float S2 = 0.f;
                for (int q = 0; q < 8; q++) S2 += sb2[par][q];
                lse[r] = mm + logf(S2);
            }
        }
    }
    float* ps = psum + (size_t)chunk * K_ + k0;
#pragma unroll
    for (int j = 0; j < 8; j++) ps[j] = acc[j];
}

// ---- updC: C <- C/(C*S + eps), S = sum over the batch's 64 chunks ----
__global__ __launch_bounds__(256) void k_updC(const float* __restrict__ psum, float* __restrict__ Cc) {
    int i = blockIdx.x * 256 + threadIdx.x;  // b*4096 + k
    int b = i >> 12, k = i & 4095;
    const float* p = psum + (size_t)(b * 64) * K_ + k;
    float s = 0.f;
#pragma unroll 8
    for (int ch = 0; ch < 64; ch++) s += p[(size_t)ch * K_];
    float c = Cc[i];
    Cc[i] = c / (c * s + SKEPS);
}

// ---- final fused pass: rowpass2 -> R2 in-reg; write assignments; loss partials ----
__global__ __launch_bounds__(512) void k_passF(float* __restrict__ Lg,
                                               const float* __restrict__ Dv,
                                               const float* __restrict__ Cc,
                                               const float* __restrict__ Rv,
                                               const float* __restrict__ lse,
                                               float* __restrict__ lossp) {
    int chunk = blockIdx.x;
    int b = chunk >> 6;
    int t = threadIdx.x;
    int k0 = t * 8;
    const float* Db = Dv + (size_t)b * K_ + k0;
    const float* Cb = Cc + (size_t)b * K_ + k0;
    float Dr[8], Cr[8];
#pragma unroll
    for (int j = 0; j < 8; j++) { Dr[j] = Db[j]; Cr[j] = Cb[j]; }
    __shared__ float sbS[2][8];
    __shared__ float sbL[8];
    int wv = t >> 6;
    float lp = 0.f;
    for (int rr = 0; rr < CH_ROWS; ++rr) {
        int r = chunk * CH_ROWS + rr;
        float* row = Lg + (size_t)r * K_;
        f32x4 La = *(const f32x4*)(row + k0);
        f32x4 Lb = *(const f32x4*)(row + k0 + 4);
        float Lv[8] = {La[0], La[1], La[2], La[3], Lb[0], Lb[1], Lb[2], Lb[3]};
        float e[8];
        float dotp = 0.f;
#pragma unroll
        for (int j = 0; j < 8; j++) {
            e[j] = __expf(Lv[j] * (1.0f / TT) + Dr[j]);
            dotp += e[j] * Cr[j];
        }
        dotp = waveReduceSum(dotp);
        int par = rr & 1;
        if ((t & 63) == 0) sbS[par][wv] = dotp;
        __syncthreads();
        float T = 0.f;
#pragma unroll
        for (int q = 0; q < 8; q++) T += sbS[par][q];
        float Rprev = Rv[r];
        float R2 = Rprev / (Rprev * T + SKEPS);
        float ls = lse[r];
        f32x4 oa, ob;
#pragma unroll
        for (int j = 0; j < 8; j++) {
            float a = R2 * e[j] * Cr[j];
            lp += a * (Lv[j] * (1.0f / PT) - ls);
            if (j < 4) oa[j] = a; else ob[j - 4] = a;
        }
        *(f32x4*)(row + k0) = oa;
        *(f32x4*)(row + k0 + 4) = ob;
    }
    lp = waveReduceSum(lp);
    if ((t & 63) == 0) sbL[wv] = lp;
    __syncthreads();
    if (t == 0) {
        float tot = 0.f;
        for (int q = 0; q < 8; q++) tot += sbL[q];
        lossp[chunk] = tot;
    }
}

__global__ __launch_bounds__(512) void k_loss(const float* __restrict__ lossp, float* __restrict__ out) {
    int t = threadIdx.x;
    float s = lossp[t];  // 512 chunks, 512 threads
    s = waveReduceSum(s);
    __shared__ float sb[8];
    if ((t & 63) == 0) sb[t >> 6] = s;
    __syncthreads();
    if (t == 0) {
        float tot = 0.f;
        for (int q = 0; q < 8; q++) tot += sb[q];
        out[LOGITS_ELEMS] = -tot / (float)R_ROWS;
    }
}

extern "C" void kernel_launch(void* const* d_in, const int* in_sizes, int n_in,
                              void* d_out, int out_size, void* d_ws, size_t ws_size,
                              hipStream_t stream) {
    const float* x = (const float*)d_in[0];
    const float* W = (const float*)d_in[1];
    const float* bias = (const float*)d_in[2];
    char* ws = (char*)d_ws;
    __hip_bfloat16* Ap = (__hip_bfloat16*)(ws + OFF_APACK);
    __hip_bfloat16* Bp = (__hip_bfloat16*)(ws + OFF_BPACK);
    float* psum = (float*)(ws + OFF_PSUM);   // aliases Bp (dead after GEMM)
    float* pmax = (float*)(ws + OFF_PMAX);
    float* psum0 = (float*)(ws + OFF_PSUM0);
    float* Dv = (float*)(ws + OFF_D);
    float* Cc = (float*)(ws + OFF_C);
    float* R = (float*)(ws + OFF_R);
    float* lse = (float*)(ws + OFF_LSE);
    float* lossp = (float*)(ws + OFF_LOSSP);
    float* out = (float*)d_out;
    float* Lg = out;  // logits live in d_out; final pass overwrites in place

    k_pack_x<<<dim3(R_ROWS), dim3(256), 0, stream>>>(x, Ap);
    k_pack_w<<<dim3(K_), dim3(256), 0, stream>>>(W, Bp);
    k_gemm<<<dim3(K_ / 128, R_ROWS / 128), dim3(256), 0, stream>>>(Ap, Bp, bias, Lg, pmax, psum0);
    k_prep<<<dim3(128), dim3(256), 0, stream>>>(pmax, psum0, Dv, Cc);
    // it0 row + it1 colsum + LSE
    k_pass<true><<<dim3(NCHUNK), dim3(512), 0, stream>>>(Lg, Dv, Cc, R, psum, lse);
    k_updC<<<dim3(128), dim3(256), 0, stream>>>(psum, Cc);
    // it1 row + it2 colsum
    k_pass<false><<<dim3(NCHUNK), dim3(512), 0, stream>>>(Lg, Dv, Cc, R, psum, lse);
    k_updC<<<dim3(128), dim3(256), 0, stream>>>(psum, Cc);
    // it2 row + assignments + loss partials
    k_passF<<<dim3(NCHUNK), dim3(512), 0, stream>>>(Lg, Dv, Cc, R, lse, lossp);
    k_loss<<<dim3(1), dim3(512), 0, stream>>>(lossp, out);
}

// Round 7
// 418.270 us; speedup vs baseline: 1.5669x; 1.1149x over previous
//
#include <hip/hip_runtime.h>
#include <hip/hip_bf16.h>
#include <stdint.h>

#define TT 0.06f
#define PT 0.12f
#define EXPMAX 50.0f
#define SKEPS 1e-8f

typedef __attribute__((ext_vector_type(8))) short short8;
typedef __attribute__((ext_vector_type(4))) float f32x4;

static constexpr int B_ = 8, N_ = 1024, D_ = 768, K_ = 4096;
static constexpr int R_ROWS = B_ * N_;                    // 8192
static constexpr long LOGITS_ELEMS = (long)R_ROWS * K_;   // 33554432
static constexpr int KP = 3 * D_;                         // 2304 packed K
static constexpr int NKT = KP / 64;                       // 36 K-tiles of 64
static constexpr int CH_ROWS = 16;                        // rows per chunk in fused passes
static constexpr int NCHUNK = R_ROWS / CH_ROWS;           // 512

// ws layout (bytes). psum aliases BPACK (Bp dead after GEMM).
static constexpr size_t OFF_APACK = 0;                                    // 37,748,736
static constexpr size_t OFF_BPACK = OFF_APACK + (size_t)R_ROWS * KP * 2;  // +18,874,368
static constexpr size_t OFF_PSUM  = OFF_BPACK;                            // 512*4096*4 = 8 MB (alias)
static constexpr size_t OFF_PMAX  = OFF_BPACK + (size_t)K_ * KP * 2;      // 32*4096*4
static constexpr size_t OFF_PSUM0 = OFF_PMAX + (size_t)64 * K_ * 4;
static constexpr size_t OFF_D     = OFF_PSUM0 + (size_t)64 * K_ * 4;
static constexpr size_t OFF_C     = OFF_D + (size_t)B_ * K_ * 4;
static constexpr size_t OFF_R     = OFF_C + (size_t)B_ * K_ * 4;
static constexpr size_t OFF_LSE   = OFF_R + (size_t)R_ROWS * 4;
static constexpr size_t OFF_LOSSP = OFF_LSE + (size_t)R_ROWS * 4;

__device__ __forceinline__ float waveReduceSum(float v) {
#pragma unroll
    for (int m = 1; m < 64; m <<= 1) v += __shfl_xor(v, m, 64);
    return v;
}
__device__ __forceinline__ float waveReduceMax(float v) {
#pragma unroll
    for (int m = 1; m < 64; m <<= 1) v = fmaxf(v, __shfl_xor(v, m, 64));
    return v;
}

// async global->LDS, 16B per lane; LDS dest = wave-uniform base + lane*16
__device__ __forceinline__ void gload_lds16(const __hip_bfloat16* g, __hip_bfloat16* l) {
    __builtin_amdgcn_global_load_lds((const __attribute__((address_space(1))) void*)g,
                                     (__attribute__((address_space(3))) void*)l, 16, 0, 0);
}

// ---- pack x: normalize rows, split to bf16 hi/lo, layout [hi | hi | lo] ----
__global__ __launch_bounds__(256) void k_pack_x(const float* __restrict__ x,
                                                __hip_bfloat16* __restrict__ Ap) {
    int r = blockIdx.x;
    const float* xr = x + (size_t)r * D_;
    int t = threadIdx.x;
    float v0 = xr[t], v1 = xr[t + 256], v2 = xr[t + 512];
    float ss = v0 * v0 + v1 * v1 + v2 * v2;
    ss = waveReduceSum(ss);
    __shared__ float sb[4];
    __shared__ float sscale;
    if ((t & 63) == 0) sb[t >> 6] = ss;
    __syncthreads();
    if (t == 0) {
        float s = sb[0] + sb[1] + sb[2] + sb[3];
        sscale = 1.0f / fmaxf(sqrtf(s), 1e-7f);
    }
    __syncthreads();
    float sc = sscale;
    __hip_bfloat16* ar = Ap + (size_t)r * KP;
    float vv[3] = {v0, v1, v2};
#pragma unroll
    for (int i = 0; i < 3; i++) {
        int d = t + i * 256;
        float xn = vv[i] * sc;
        __hip_bfloat16 hi = __float2bfloat16(xn);
        float lo = xn - __bfloat162float(hi);
        ar[d] = hi;
        ar[768 + d] = hi;
        ar[1536 + d] = __float2bfloat16(lo);
    }
}

// ---- pack W: split to bf16 hi/lo, layout [hi | lo | hi] ----
__global__ __launch_bounds__(256) void k_pack_w(const float* __restrict__ Wg,
                                                __hip_bfloat16* __restrict__ Bp) {
    int kk = blockIdx.x;
    const float* wr = Wg + (size_t)kk * D_;
    __hip_bfloat16* br = Bp + (size_t)kk * KP;
    int t = threadIdx.x;
#pragma unroll
    for (int i = 0; i < 3; i++) {
        int d = t + i * 256;
        float v = wr[d];
        __hip_bfloat16 hi = __float2bfloat16(v);
        float lo = v - __bfloat162float(hi);
        br[d] = hi;
        br[768 + d] = __float2bfloat16(lo);
        br[1536 + d] = hi;
    }
}

// ---- GEMM 256x256 tile, BK=64, 8 waves, depth-2 dbuf, swizzled LDS, phased MFMA.
// Fused col-max AND col-exp-sum partials over the block's 256 rows. ----
__global__ __launch_bounds__(512, 2) void k_gemm(const __hip_bfloat16* __restrict__ Ap,
                                                 const __hip_bfloat16* __restrict__ Bp,
                                                 const float* __restrict__ bias,
                                                 float* __restrict__ Lg,
                                                 float* __restrict__ pmax,
                                                 float* __restrict__ psum0) {
    extern __shared__ __align__(16) char ldsbuf[];  // [2][32KB] A, then [2][32KB] B = 128 KB
    __shared__ float sm_cmax[8][64];
    __shared__ float sm_csum[8][64];
    __shared__ float sm_bmax[256];

    int tid = threadIdx.x;
    int lane = tid & 63, w = tid >> 6;
    int bn = blockIdx.x, bm = blockIdx.y;
    int wm = w >> 2, wn = w & 3;         // 2M x 4N wave grid; wave owns 128x64 output
    int laneM = lane & 15, kq = lane >> 4;

    // staging: call q covers tile rows q*64..q*64+63; wave w rows w*8+(lane>>3) of that.
    // LDS written linearly; global source pre-swizzled: chunk = (lane&7) ^ (row&7).
    const __hip_bfloat16* srcA =
        Ap + (size_t)(bm * 256 + w * 8 + (lane >> 3)) * KP + (((lane & 7) ^ (lane >> 3)) * 8);
    const __hip_bfloat16* srcB =
        Bp + (size_t)(bn * 256 + w * 8 + (lane >> 3)) * KP + (((lane & 7) ^ (lane >> 3)) * 8);

    // read-side swizzle: byte = row*128 + ((chunk ^ (row&7))*16); row&7 == lane&7 here.
    int swz0 = ((kq ^ (lane & 7)) << 4);
    int aBase = ((wm * 128 + laneM) << 7) + swz0;  // + i*2048, ^ (s<<6)
    int bBase = ((wn * 64 + laneM) << 7) + swz0;   // + j*2048, ^ (s<<6)

    f32x4 acc[8][4];
#pragma unroll
    for (int i = 0; i < 8; i++)
#pragma unroll
        for (int j = 0; j < 4; j++) acc[i][j] = (f32x4){0.f, 0.f, 0.f, 0.f};

    // prologue: stage tile 0 into buf 0
#pragma unroll
    for (int q = 0; q < 4; ++q) {
        gload_lds16(srcA + (size_t)q * 64 * KP, (__hip_bfloat16*)(ldsbuf + q * 8192 + w * 1024));
        gload_lds16(srcB + (size_t)q * 64 * KP, (__hip_bfloat16*)(ldsbuf + 65536 + q * 8192 + w * 1024));
    }
    asm volatile("s_waitcnt vmcnt(0)" ::: "memory");
    __builtin_amdgcn_s_barrier();
    __builtin_amdgcn_sched_barrier(0);

    int cur = 0;
    for (int t = 0; t < NKT; ++t) {
        char* Ab = ldsbuf + cur * 32768;
        char* Bb = ldsbuf + 65536 + cur * 32768;
        if (t < NKT - 1) {
            const __hip_bfloat16* nA = srcA + (size_t)(t + 1) * 64;
            const __hip_bfloat16* nB = srcB + (size_t)(t + 1) * 64;
            char* dA = ldsbuf + (cur ^ 1) * 32768;
            char* dB = ldsbuf + 65536 + (cur ^ 1) * 32768;
#pragma unroll
            for (int q = 0; q < 4; ++q) {
                gload_lds16(nA + (size_t)q * 64 * KP, (__hip_bfloat16*)(dA + q * 8192 + w * 1024));
                gload_lds16(nB + (size_t)q * 64 * KP, (__hip_bfloat16*)(dB + q * 8192 + w * 1024));
            }
        }
        short8 bf[4][2];
#pragma unroll
        for (int j = 0; j < 4; ++j)
#pragma unroll
            for (int s = 0; s < 2; ++s)
                bf[j][s] = *(const short8*)(Bb + ((bBase + j * 2048) ^ (s << 6)));
#pragma unroll
        for (int p = 0; p < 4; ++p) {
            short8 af[2][2];
#pragma unroll
            for (int ii = 0; ii < 2; ++ii)
#pragma unroll
                for (int s = 0; s < 2; ++s)
                    af[ii][s] = *(const short8*)(Ab + ((aBase + (p * 2 + ii) * 2048) ^ (s << 6)));
            __builtin_amdgcn_s_barrier();
            __builtin_amdgcn_sched_barrier(0);
            __builtin_amdgcn_s_setprio(1);
#pragma unroll
            for (int ii = 0; ii < 2; ++ii)
#pragma unroll
                for (int j = 0; j < 4; ++j)
#pragma unroll
                    for (int s = 0; s < 2; ++s)
                        acc[p * 2 + ii][j] = __builtin_amdgcn_mfma_f32_16x16x32_bf16(
                            af[ii][s], bf[j][s], acc[p * 2 + ii][j], 0, 0, 0);
            __builtin_amdgcn_s_setprio(0);
            __builtin_amdgcn_sched_barrier(0);
            if (p < 3) {
                __builtin_amdgcn_s_barrier();
                __builtin_amdgcn_sched_barrier(0);
            }
        }
        asm volatile("s_waitcnt vmcnt(0)" ::: "memory");
        __builtin_amdgcn_s_barrier();
        __builtin_amdgcn_sched_barrier(0);
        cur ^= 1;
    }

    // epilogue: write logits + fused per-column block max / exp-sum (256 rows)
    int colg0 = bn * 256 + wn * 64;
    int rowg0 = bm * 256 + wm * 128;
    float bbv[4];
#pragma unroll
    for (int j = 0; j < 4; ++j) {
        int colg = colg0 + j * 16 + laneM;
        float bb = bias[colg];
        bbv[j] = bb;
        float mx = -3.4e38f;
#pragma unroll
        for (int i = 0; i < 8; ++i) {
            int rowg = rowg0 + i * 16 + kq * 4;
#pragma unroll
            for (int rr = 0; rr < 4; ++rr) {
                float v = acc[i][j][rr] + bb;
                Lg[(size_t)(rowg + rr) * K_ + colg] = v;
                mx = fmaxf(mx, v);
            }
        }
        mx = fmaxf(mx, __shfl_xor(mx, 16, 64));
        mx = fmaxf(mx, __shfl_xor(mx, 32, 64));
        if (kq == 0) sm_cmax[w][j * 16 + laneM] = mx;
    }
    __syncthreads();
    if (tid < 256) {
        int wn_t = tid >> 6, ci = tid & 63;
        float m = fmaxf(sm_cmax[wn_t][ci], sm_cmax[wn_t + 4][ci]);
        sm_bmax[tid] = m;
        pmax[(size_t)bm * K_ + bn * 256 + tid] = m;
    }
    __syncthreads();
#pragma unroll
    for (int j = 0; j < 4; ++j) {
        float M = sm_bmax[wn * 64 + j * 16 + laneM];
        float s = 0.f;
#pragma unroll
        for (int i = 0; i < 8; ++i)
#pragma unroll
            for (int rr = 0; rr < 4; ++rr)
                s += __expf((acc[i][j][rr] + bbv[j] - M) * (1.0f / TT));
        s += __shfl_xor(s, 16, 64);
        s += __shfl_xor(s, 32, 64);
        if (kq == 0) sm_csum[w][j * 16 + laneM] = s;
    }
    __syncthreads();
    if (tid < 256) {
        int wn_t = tid >> 6, ci = tid & 63;
        psum0[(size_t)bm * K_ + bn * 256 + tid] = sm_csum[wn_t][ci] + sm_csum[wn_t + 4][ci];
    }
}

// ---- prep: per (b,k): D = 50 - colmax/TT ; S0 = sum_strips P*exp(m/TT + D) ; C0 = 1/(S0+eps) ----
__global__ __launch_bounds__(256) void k_prep(const float* __restrict__ pmax,
                                              const float* __restrict__ psum0,
                                              float* __restrict__ Dv,
                                              float* __restrict__ Cc) {
    int i = blockIdx.x * 256 + threadIdx.x;  // b*4096 + k
    int b = i >> 12, k = i & 4095;
    float mv[4];
    float m = -3.4e38f;
#pragma unroll
    for (int nc = 0; nc < 4; nc++) {
        mv[nc] = pmax[(size_t)(b * 4 + nc) * K_ + k];
        m = fmaxf(m, mv[nc]);
    }
    float Dd = EXPMAX - m * (1.0f / TT);
    float S0 = 0.f;
#pragma unroll
    for (int nc = 0; nc < 4; nc++)
        S0 += psum0[(size_t)(b * 4 + nc) * K_ + k] * __expf(mv[nc] * (1.0f / TT) + Dd);
    Dv[i] = Dd;
    Cc[i] = 1.0f / (S0 + SKEPS);
}

// ---- fused pass: per row: T = sum e*C -> R_new ; accumulate R_new*e into col partials.
// FIRST: R_prev = 1 and also computes row LSE of L/PT. ----
template <bool FIRST>
__global__ __launch_bounds__(512) void k_pass(const float* __restrict__ Lg,
                                              const float* __restrict__ Dv,
                                              const float* __restrict__ Cc,
                                              float* __restrict__ Rv,
                                              float* __restrict__ psum,
                                              float* __restrict__ lse) {
    int chunk = blockIdx.x;  // 0..511
    int b = chunk >> 6;
    int t = threadIdx.x;
    int k0 = t * 8;
    const float* Db = Dv + (size_t)b * K_ + k0;
    const float* Cb = Cc + (size_t)b * K_ + k0;
    float Dr[8], Cr[8], acc[8];
#pragma unroll
    for (int j = 0; j < 8; j++) { Dr[j] = Db[j]; Cr[j] = Cb[j]; acc[j] = 0.f; }
    __shared__ float sbS[2][8], sbM[2][8], sb2[2][8];
    int wv = t >> 6;
    for (int rr = 0; rr < CH_ROWS; ++rr) {
        int r = chunk * CH_ROWS + rr;
        const float* row = Lg + (size_t)r * K_;
        f32x4 La = *(const f32x4*)(row + k0);
        f32x4 Lb = *(const f32x4*)(row + k0 + 4);
        float Lv[8] = {La[0], La[1], La[2], La[3], Lb[0], Lb[1], Lb[2], Lb[3]};
        float e[8];
        float dotp = 0.f, mxl = -3.4e38f;
#pragma unroll
        for (int j = 0; j < 8; j++) {
            e[j] = __expf(Lv[j] * (1.0f / TT) + Dr[j]);
            dotp += e[j] * Cr[j];
            if (FIRST) mxl = fmaxf(mxl, Lv[j]);
        }
        dotp = waveReduceSum(dotp);
        if (FIRST) mxl = waveReduceMax(mxl);
        int par = rr & 1;
        if ((t & 63) == 0) {
            sbS[par][wv] = dotp;
            if (FIRST) sbM[par][wv] = mxl;
        }
        __syncthreads();
        float T = 0.f, MX = -3.4e38f;
#pragma unroll
        for (int q = 0; q < 8; q++) {
            T += sbS[par][q];
            if (FIRST) MX = fmaxf(MX, sbM[par][q]);
        }
        float Rprev = FIRST ? 1.0f : Rv[r];
        float Rnew = Rprev / (Rprev * T + SKEPS);
#pragma unroll
        for (int j = 0; j < 8; j++) acc[j] += Rnew * e[j];
        if (t == 0) Rv[r] = Rnew;
        if (FIRST) {
            float mm = MX * (1.0f / PT);
            float s2 = 0.f;
#pragma unroll
            for (int j = 0; j < 8; j++) s2 += __expf(Lv[j] * (1.0f / PT) - mm);
            s2 = waveReduceSum(s2);
            if ((t & 63) == 0) sb2[par][wv] = s2;
            __syncthreads();
            if (t == 0) {
                float S2 = 0.f;
                for (int q = 0; q < 8; q++) S2 += sb2[par][q];
                lse[r] = mm + logf(S2);
            }
        }
    }
    float* ps = psum + (size_t)chunk * K_ + k0;
#pragma unroll
    for (int j = 0; j < 8; j++) ps[j] = acc[j];
}

// ---- updC: C <- C/(C*S + eps), S = sum over the batch's 64 chunks ----
__global__ __launch_bounds__(256) void k_updC(const float* __restrict__ psum, float* __restrict__ Cc) {
    int i = blockIdx.x * 256 + threadIdx.x;  // b*4096 + k
    int b = i >> 12, k = i & 4095;
    const float* p = psum + (size_t)(b * 64) * K_ + k;
    float s = 0.f;
#pragma unroll 8
    for (int ch = 0; ch < 64; ch++) s += p[(size_t)ch * K_];
    float c = Cc[i];
    Cc[i] = c / (c * s + SKEPS);
}

// ---- final fused pass: rowpass2 -> R2 in-reg; write assignments; loss partials ----
__global__ __launch_bounds__(512) void k_passF(float* __restrict__ Lg,
                                               const float* __restrict__ Dv,
                                               const float* __restrict__ Cc,
                                               const float* __restrict__ Rv,
                                               const float* __restrict__ lse,
                                               float* __restrict__ lossp) {
    int chunk = blockIdx.x;
    int b = chunk >> 6;
    int t = threadIdx.x;
    int k0 = t * 8;
    const float* Db = Dv + (size_t)b * K_ + k0;
    const float* Cb = Cc + (size_t)b * K_ + k0;
    float Dr[8], Cr[8];
#pragma unroll
    for (int j = 0; j < 8; j++) { Dr[j] = Db[j]; Cr[j] = Cb[j]; }
    __shared__ float sbS[2][8];
    __shared__ float sbL[8];
    int wv = t >> 6;
    float lp = 0.f;
    for (int rr = 0; rr < CH_ROWS; ++rr) {
        int r = chunk * CH_ROWS + rr;
        float* row = Lg + (size_t)r * K_;
        f32x4 La = *(const f32x4*)(row + k0);
        f32x4 Lb = *(const f32x4*)(row + k0 + 4);
        float Lv[8] = {La[0], La[1], La[2], La[3], Lb[0], Lb[1], Lb[2], Lb[3]};
        float e[8];
        float dotp = 0.f;
#pragma unroll
        for (int j = 0; j < 8; j++) {
            e[j] = __expf(Lv[j] * (1.0f / TT) + Dr[j]);
            dotp += e[j] * Cr[j];
        }
        dotp = waveReduceSum(dotp);
        int par = rr & 1;
        if ((t & 63) == 0) sbS[par][wv] = dotp;
        __syncthreads();
        float T = 0.f;
#pragma unroll
        for (int q = 0; q < 8; q++) T += sbS[par][q];
        float Rprev = Rv[r];
        float R2 = Rprev / (Rprev * T + SKEPS);
        float ls = lse[r];
        f32x4 oa, ob;
#pragma unroll
        for (int j = 0; j < 8; j++) {
            float a = R2 * e[j] * Cr[j];
            lp += a * (Lv[j] * (1.0f / PT) - ls);
            if (j < 4) oa[j] = a; else ob[j - 4] = a;
        }
        *(f32x4*)(row + k0) = oa;
        *(f32x4*)(row + k0 + 4) = ob;
    }
    lp = waveReduceSum(lp);
    if ((t & 63) == 0) sbL[wv] = lp;
    __syncthreads();
    if (t == 0) {
        float tot = 0.f;
        for (int q = 0; q < 8; q++) tot += sbL[q];
        lossp[chunk] = tot;
    }
}

__global__ __launch_bounds__(512) void k_loss(const float* __restrict__ lossp, float* __restrict__ out) {
    int t = threadIdx.x;
    float s = lossp[t];  // 512 chunks, 512 threads
    s = waveReduceSum(s);
    __shared__ float sb[8];
    if ((t & 63) == 0) sb[t >> 6] = s;
    __syncthreads();
    if (t == 0) {
        float tot = 0.f;
        for (int q = 0; q < 8; q++) tot += sb[q];
        out[LOGITS_ELEMS] = -tot / (float)R_ROWS;
    }
}

extern "C" void kernel_launch(void* const* d_in, const int* in_sizes, int n_in,
                              void* d_out, int out_size, void* d_ws, size_t ws_size,
                              hipStream_t stream) {
    const float* x = (const float*)d_in[0];
    const float* W = (const float*)d_in[1];
    const float* bias = (const float*)d_in[2];
    char* ws = (char*)d_ws;
    __hip_bfloat16* Ap = (__hip_bfloat16*)(ws + OFF_APACK);
    __hip_bfloat16* Bp = (__hip_bfloat16*)(ws + OFF_BPACK);
    float* psum = (float*)(ws + OFF_PSUM);   // aliases Bp (dead after GEMM)
    float* pmax = (float*)(ws + OFF_PMAX);
    float* psum0 = (float*)(ws + OFF_PSUM0);
    float* Dv = (float*)(ws + OFF_D);
    float* Cc = (float*)(ws + OFF_C);
    float* R = (float*)(ws + OFF_R);
    float* lse = (float*)(ws + OFF_LSE);
    float* lossp = (float*)(ws + OFF_LOSSP);
    float* out = (float*)d_out;
    float* Lg = out;  // logits live in d_out; final pass overwrites in place

    hipFuncSetAttribute((const void*)k_gemm, hipFuncAttributeMaxDynamicSharedMemorySize, 131072);

    k_pack_x<<<dim3(R_ROWS), dim3(256), 0, stream>>>(x, Ap);
    k_pack_w<<<dim3(K_), dim3(256), 0, stream>>>(W, Bp);
    k_gemm<<<dim3(K_ / 256, R_ROWS / 256), dim3(512), 131072, stream>>>(Ap, Bp, bias, Lg, pmax, psum0);
    k_prep<<<dim3(128), dim3(256), 0, stream>>>(pmax, psum0, Dv, Cc);
    // it0 row + it1 colsum + LSE
    k_pass<true><<<dim3(NCHUNK), dim3(512), 0, stream>>>(Lg, Dv, Cc, R, psum, lse);
    k_updC<<<dim3(128), dim3(256), 0, stream>>>(psum, Cc);
    // it1 row + it2 colsum
    k_pass<false><<<dim3(NCHUNK), dim3(512), 0, stream>>>(Lg, Dv, Cc, R, psum, lse);
    k_updC<<<dim3(128), dim3(256), 0, stream>>>(psum, Cc);
    // it2 row + assignments + loss partials
    k_passF<<<dim3(NCHUNK), dim3(512), 0, stream>>>(Lg, Dv, Cc, R, lse, lossp);
    k_loss<<<dim3(1), dim3(512), 0, stream>>>(lossp, out);
}

// Round 8
// 415.425 us; speedup vs baseline: 1.5776x; 1.0068x over previous
//
#include <hip/hip_runtime.h>
#include <hip/hip_bf16.h>
#include <stdint.h>

#define TT 0.06f
#define PT 0.12f
#define EXPMAX 50.0f
#define SKEPS 1e-8f

typedef __attribute__((ext_vector_type(8))) short short8;
typedef __attribute__((ext_vector_type(8))) unsigned short ushort8;
typedef __attribute__((ext_vector_type(4))) float f32x4;

static constexpr int B_ = 8, N_ = 1024, D_ = 768, K_ = 4096;
static constexpr int R_ROWS = B_ * N_;                    // 8192
static constexpr long LOGITS_ELEMS = (long)R_ROWS * K_;   // 33554432
static constexpr int KP = 3 * D_;                         // 2304 packed K
static constexpr int NKT = KP / 64;                       // 36 K-tiles of 64
static constexpr int CH_ROWS = 16;                        // rows per chunk in fused passes
static constexpr int NCHUNK = R_ROWS / CH_ROWS;           // 512
// int16 logits: row r occupies the first 8KB of row r's 16KB d_out slot.
// q = rint(L * 4096); L_q = q / 4096.  |L|max ~5.6 << 8 (range), step 2.44e-4.
#define QS 4096.0f
#define IQS 2.44140625e-4f
static constexpr int LQ_STRIDE = 2 * K_;  // ushorts per row slot (8192)

// ws layout (bytes). psum aliases BPACK (Bp dead after GEMM).
static constexpr size_t OFF_APACK = 0;
static constexpr size_t OFF_BPACK = OFF_APACK + (size_t)R_ROWS * KP * 2;
static constexpr size_t OFF_PSUM  = OFF_BPACK;                            // 512*4096*4 (alias)
static constexpr size_t OFF_PMAX  = OFF_BPACK + (size_t)K_ * KP * 2;
static constexpr size_t OFF_PSUM0 = OFF_PMAX + (size_t)64 * K_ * 4;
static constexpr size_t OFF_D     = OFF_PSUM0 + (size_t)64 * K_ * 4;
static constexpr size_t OFF_C     = OFF_D + (size_t)B_ * K_ * 4;
static constexpr size_t OFF_R     = OFF_C + (size_t)B_ * K_ * 4;
static constexpr size_t OFF_LSE   = OFF_R + (size_t)R_ROWS * 4;
static constexpr size_t OFF_LOSSP = OFF_LSE + (size_t)R_ROWS * 4;

__device__ __forceinline__ float waveReduceSum(float v) {
#pragma unroll
    for (int m = 1; m < 64; m <<= 1) v += __shfl_xor(v, m, 64);
    return v;
}
__device__ __forceinline__ float waveReduceMax(float v) {
#pragma unroll
    for (int m = 1; m < 64; m <<= 1) v = fmaxf(v, __shfl_xor(v, m, 64));
    return v;
}

__device__ __forceinline__ void gload_lds16(const __hip_bfloat16* g, __hip_bfloat16* l) {
    __builtin_amdgcn_global_load_lds((const __attribute__((address_space(1))) void*)g,
                                     (__attribute__((address_space(3))) void*)l, 16, 0, 0);
}

// ---- merged pack: blocks [0,8192) do x-rows, [8192,12288) do W-rows ----
__global__ __launch_bounds__(256) void k_pack(const float* __restrict__ x,
                                              const float* __restrict__ Wg,
                                              __hip_bfloat16* __restrict__ Ap,
                                              __hip_bfloat16* __restrict__ Bp) {
    int blk = blockIdx.x;
    int t = threadIdx.x;
    if (blk < R_ROWS) {
        int r = blk;
        const float* xr = x + (size_t)r * D_;
        float v0 = xr[t], v1 = xr[t + 256], v2 = xr[t + 512];
        float ss = v0 * v0 + v1 * v1 + v2 * v2;
        ss = waveReduceSum(ss);
        __shared__ float sb[4];
        __shared__ float sscale;
        if ((t & 63) == 0) sb[t >> 6] = ss;
        __syncthreads();
        if (t == 0) {
            float s = sb[0] + sb[1] + sb[2] + sb[3];
            sscale = 1.0f / fmaxf(sqrtf(s), 1e-7f);
        }
        __syncthreads();
        float sc = sscale;
        __hip_bfloat16* ar = Ap + (size_t)r * KP;
        float vv[3] = {v0, v1, v2};
#pragma unroll
        for (int i = 0; i < 3; i++) {
            int d = t + i * 256;
            float xn = vv[i] * sc;
            __hip_bfloat16 hi = __float2bfloat16(xn);
            float lo = xn - __bfloat162float(hi);
            ar[d] = hi;
            ar[768 + d] = hi;
            ar[1536 + d] = __float2bfloat16(lo);
        }
    } else {
        int kk = blk - R_ROWS;
        const float* wr = Wg + (size_t)kk * D_;
        __hip_bfloat16* br = Bp + (size_t)kk * KP;
#pragma unroll
        for (int i = 0; i < 3; i++) {
            int d = t + i * 256;
            float v = wr[d];
            __hip_bfloat16 hi = __float2bfloat16(v);
            float lo = v - __bfloat162float(hi);
            br[d] = hi;
            br[768 + d] = __float2bfloat16(lo);
            br[1536 + d] = hi;
        }
    }
}

// ---- GEMM 256x256, BK=64, 8 waves, dbuf, swizzled LDS; int16-quantized logit store;
// fused per-column block max / exp-sum over quantized values ----
__global__ __launch_bounds__(512, 2) void k_gemm(const __hip_bfloat16* __restrict__ Ap,
                                                 const __hip_bfloat16* __restrict__ Bp,
                                                 const float* __restrict__ bias,
                                                 float* Lg,
                                                 float* __restrict__ pmax,
                                                 float* __restrict__ psum0) {
    extern __shared__ __align__(16) char ldsbuf[];  // [2][32KB] A, then [2][32KB] B
    __shared__ float sm_cmax[8][64];
    __shared__ float sm_csum[8][64];
    __shared__ float sm_bmax[256];

    int tid = threadIdx.x;
    int lane = tid & 63, w = tid >> 6;
    // XCD-aware bijective swizzle (nwg=512, 8 XCDs, 64 per XCD)
    int wgid = blockIdx.y * 16 + blockIdx.x;
    int nid = (wgid & 7) * 64 + (wgid >> 3);
    int bn = nid & 15, bm = nid >> 4;
    int wm = w >> 2, wn = w & 3;
    int laneM = lane & 15, kq = lane >> 4;

    const __hip_bfloat16* srcA =
        Ap + (size_t)(bm * 256 + w * 8 + (lane >> 3)) * KP + (((lane & 7) ^ (lane >> 3)) * 8);
    const __hip_bfloat16* srcB =
        Bp + (size_t)(bn * 256 + w * 8 + (lane >> 3)) * KP + (((lane & 7) ^ (lane >> 3)) * 8);

    int swz0 = ((kq ^ (lane & 7)) << 4);
    int aBase = ((wm * 128 + laneM) << 7) + swz0;
    int bBase = ((wn * 64 + laneM) << 7) + swz0;

    f32x4 acc[8][4];
#pragma unroll
    for (int i = 0; i < 8; i++)
#pragma unroll
        for (int j = 0; j < 4; j++) acc[i][j] = (f32x4){0.f, 0.f, 0.f, 0.f};

#pragma unroll
    for (int q = 0; q < 4; ++q) {
        gload_lds16(srcA + (size_t)q * 64 * KP, (__hip_bfloat16*)(ldsbuf + q * 8192 + w * 1024));
        gload_lds16(srcB + (size_t)q * 64 * KP, (__hip_bfloat16*)(ldsbuf + 65536 + q * 8192 + w * 1024));
    }
    asm volatile("s_waitcnt vmcnt(0)" ::: "memory");
    __builtin_amdgcn_s_barrier();
    __builtin_amdgcn_sched_barrier(0);

    int cur = 0;
    for (int t = 0; t < NKT; ++t) {
        char* Ab = ldsbuf + cur * 32768;
        char* Bb = ldsbuf + 65536 + cur * 32768;
        if (t < NKT - 1) {
            const __hip_bfloat16* nA = srcA + (size_t)(t + 1) * 64;
            const __hip_bfloat16* nB = srcB + (size_t)(t + 1) * 64;
            char* dA = ldsbuf + (cur ^ 1) * 32768;
            char* dB = ldsbuf + 65536 + (cur ^ 1) * 32768;
#pragma unroll
            for (int q = 0; q < 4; ++q) {
                gload_lds16(nA + (size_t)q * 64 * KP, (__hip_bfloat16*)(dA + q * 8192 + w * 1024));
                gload_lds16(nB + (size_t)q * 64 * KP, (__hip_bfloat16*)(dB + q * 8192 + w * 1024));
            }
        }
        short8 bf[4][2];
#pragma unroll
        for (int j = 0; j < 4; ++j)
#pragma unroll
            for (int s = 0; s < 2; ++s)
                bf[j][s] = *(const short8*)(Bb + ((bBase + j * 2048) ^ (s << 6)));
#pragma unroll
        for (int p = 0; p < 4; ++p) {
            short8 af[2][2];
#pragma unroll
            for (int ii = 0; ii < 2; ++ii)
#pragma unroll
                for (int s = 0; s < 2; ++s)
                    af[ii][s] = *(const short8*)(Ab + ((aBase + (p * 2 + ii) * 2048) ^ (s << 6)));
            __builtin_amdgcn_s_barrier();
            __builtin_amdgcn_sched_barrier(0);
            __builtin_amdgcn_s_setprio(1);
#pragma unroll
            for (int ii = 0; ii < 2; ++ii)
#pragma unroll
                for (int j = 0; j < 4; ++j)
#pragma unroll
                    for (int s = 0; s < 2; ++s)
                        acc[p * 2 + ii][j] = __builtin_amdgcn_mfma_f32_16x16x32_bf16(
                            af[ii][s], bf[j][s], acc[p * 2 + ii][j], 0, 0, 0);
            __builtin_amdgcn_s_setprio(0);
            __builtin_amdgcn_sched_barrier(0);
            if (p < 3) {
                __builtin_amdgcn_s_barrier();
                __builtin_amdgcn_sched_barrier(0);
            }
        }
        asm volatile("s_waitcnt vmcnt(0)" ::: "memory");
        __builtin_amdgcn_s_barrier();
        __builtin_amdgcn_sched_barrier(0);
        cur ^= 1;
    }

    // epilogue: quantize -> int16 store into row-local slots; col stats on v_q
    unsigned short* Lq = (unsigned short*)Lg;
    int colg0 = bn * 256 + wn * 64;
    int rowg0 = bm * 256 + wm * 128;
    float bbv[4];
#pragma unroll
    for (int j = 0; j < 4; ++j) {
        int colg = colg0 + j * 16 + laneM;
        float bb = bias[colg];
        bbv[j] = bb;
        float mx = -3.4e38f;
#pragma unroll
        for (int i = 0; i < 8; ++i) {
            int rowg = rowg0 + i * 16 + kq * 4;
#pragma unroll
            for (int rr = 0; rr < 4; ++rr) {
                float v = acc[i][j][rr] + bb;
                int qi = __float2int_rn(v * QS);
                qi = max(-32768, min(32767, qi));
                float vq = (float)qi * IQS;
                Lq[(size_t)(rowg + rr) * LQ_STRIDE + colg] = (unsigned short)(short)qi;
                mx = fmaxf(mx, vq);
            }
        }
        mx = fmaxf(mx, __shfl_xor(mx, 16, 64));
        mx = fmaxf(mx, __shfl_xor(mx, 32, 64));
        if (kq == 0) sm_cmax[w][j * 16 + laneM] = mx;
    }
    __syncthreads();
    if (tid < 256) {
        int wn_t = tid >> 6, ci = tid & 63;
        float m = fmaxf(sm_cmax[wn_t][ci], sm_cmax[wn_t + 4][ci]);
        sm_bmax[tid] = m;
        pmax[(size_t)bm * K_ + bn * 256 + tid] = m;
    }
    __syncthreads();
#pragma unroll
    for (int j = 0; j < 4; ++j) {
        float M = sm_bmax[wn * 64 + j * 16 + laneM];
        float s = 0.f;
#pragma unroll
        for (int i = 0; i < 8; ++i)
#pragma unroll
            for (int rr = 0; rr < 4; ++rr) {
                float v = acc[i][j][rr] + bbv[j];
                int qi = __float2int_rn(v * QS);
                qi = max(-32768, min(32767, qi));
                float vq = (float)qi * IQS;
                s += __expf((vq - M) * (1.0f / TT));
            }
        s += __shfl_xor(s, 16, 64);
        s += __shfl_xor(s, 32, 64);
        if (kq == 0) sm_csum[w][j * 16 + laneM] = s;
    }
    __syncthreads();
    if (tid < 256) {
        int wn_t = tid >> 6, ci = tid & 63;
        psum0[(size_t)bm * K_ + bn * 256 + tid] = sm_csum[wn_t][ci] + sm_csum[wn_t + 4][ci];
    }
}

// ---- prep: per (b,k): D = 50 - colmax/TT ; S0 ; C0 = 1/(S0+eps) ----
__global__ __launch_bounds__(256) void k_prep(const float* __restrict__ pmax,
                                              const float* __restrict__ psum0,
                                              float* __restrict__ Dv,
                                              float* __restrict__ Cc) {
    int i = blockIdx.x * 256 + threadIdx.x;
    int b = i >> 12, k = i & 4095;
    float mv[4];
    float m = -3.4e38f;
#pragma unroll
    for (int nc = 0; nc < 4; nc++) {
        mv[nc] = pmax[(size_t)(b * 4 + nc) * K_ + k];
        m = fmaxf(m, mv[nc]);
    }
    float Dd = EXPMAX - m * (1.0f / TT);
    float S0 = 0.f;
#pragma unroll
    for (int nc = 0; nc < 4; nc++)
        S0 += psum0[(size_t)(b * 4 + nc) * K_ + k] * __expf(mv[nc] * (1.0f / TT) + Dd);
    Dv[i] = Dd;
    Cc[i] = 1.0f / (S0 + SKEPS);
}

// ---- fused pass over int16 logits, prefetched rows ----
template <bool FIRST>
__global__ __launch_bounds__(512) void k_pass(const float* Lg,
                                              const float* __restrict__ Dv,
                                              const float* __restrict__ Cc,
                                              float* __restrict__ Rv,
                                              float* __restrict__ psum,
                                              float* __restrict__ lse) {
    const unsigned short* Lq = (const unsigned short*)Lg;
    int chunk = blockIdx.x;
    int b = chunk >> 6;
    int t = threadIdx.x;
    int k0 = t * 8;
    const float* Db = Dv + (size_t)b * K_ + k0;
    const float* Cb = Cc + (size_t)b * K_ + k0;
    float Dr[8], Cr[8], acc[8];
#pragma unroll
    for (int j = 0; j < 8; j++) { Dr[j] = Db[j]; Cr[j] = Cb[j]; acc[j] = 0.f; }
    __shared__ float sbS[2][8], sbM[2][8], sb2[2][8];
    int wv = t >> 6;
    ushort8 qv = *(const ushort8*)(Lq + (size_t)(chunk * CH_ROWS) * LQ_STRIDE + k0);
    for (int rr = 0; rr < CH_ROWS; ++rr) {
        int r = chunk * CH_ROWS + rr;
        float Lv[8];
#pragma unroll
        for (int j = 0; j < 8; j++) Lv[j] = (float)(short)qv[j] * IQS;
        if (rr < CH_ROWS - 1)
            qv = *(const ushort8*)(Lq + (size_t)(r + 1) * LQ_STRIDE + k0);
        float e[8];
        float dotp = 0.f, mxl = -3.4e38f;
#pragma unroll
        for (int j = 0; j < 8; j++) {
            e[j] = __expf(Lv[j] * (1.0f / TT) + Dr[j]);
            dotp += e[j] * Cr[j];
            if (FIRST) mxl = fmaxf(mxl, Lv[j]);
        }
        dotp = waveReduceSum(dotp);
        if (FIRST) mxl = waveReduceMax(mxl);
        int par = rr & 1;
        if ((t & 63) == 0) {
            sbS[par][wv] = dotp;
            if (FIRST) sbM[par][wv] = mxl;
        }
        __syncthreads();
        float T = 0.f, MX = -3.4e38f;
#pragma unroll
        for (int q = 0; q < 8; q++) {
            T += sbS[par][q];
            if (FIRST) MX = fmaxf(MX, sbM[par][q]);
        }
        float Rprev = FIRST ? 1.0f : Rv[r];
        float Rnew = Rprev / (Rprev * T + SKEPS);
#pragma unroll
        for (int j = 0; j < 8; j++) acc[j] += Rnew * e[j];
        if (t == 0) Rv[r] = Rnew;
        if (FIRST) {
            float mm = MX * (1.0f / PT);
            float s2 = 0.f;
#pragma unroll
            for (int j = 0; j < 8; j++) s2 += __expf(Lv[j] * (1.0f / PT) - mm);
            s2 = waveReduceSum(s2);
            if ((t & 63) == 0) sb2[par][wv] = s2;
            __syncthreads();
            if (t == 0) {
                float S2 = 0.f;
                for (int q = 0; q < 8; q++) S2 += sb2[par][q];
                lse[r] = mm + logf(S2);
            }
        }
    }
    float* ps = psum + (size_t)chunk * K_ + k0;
#pragma unroll
    for (int j = 0; j < 8; j++) ps[j] = acc[j];
}

// ---- updC ----
__global__ __launch_bounds__(256) void k_updC(const float* __restrict__ psum, float* __restrict__ Cc) {
    int i = blockIdx.x * 256 + threadIdx.x;
    int b = i >> 12, k = i & 4095;
    const float* p = psum + (size_t)(b * 64) * K_ + k;
    float s = 0.f;
#pragma unroll 8
    for (int ch = 0; ch < 64; ch++) s += p[(size_t)ch * K_];
    float c = Cc[i];
    Cc[i] = c / (c * s + SKEPS);
}

// ---- final: read int16 logits (row-local), write f32 assignments over full rows ----
__global__ __launch_bounds__(512) void k_passF(float* Lg,
                                               const float* __restrict__ Dv,
                                               const float* __restrict__ Cc,
                                               const float* __restrict__ Rv,
                                               const float* __restrict__ lse,
                                               float* __restrict__ lossp) {
    const unsigned short* Lq = (const unsigned short*)Lg;
    int chunk = blockIdx.x;
    int b = chunk >> 6;
    int t = threadIdx.x;
    int k0 = t * 8;
    const float* Db = Dv + (size_t)b * K_ + k0;
    const float* Cb = Cc + (size_t)b * K_ + k0;
    float Dr[8], Cr[8];
#pragma unroll
    for (int j = 0; j < 8; j++) { Dr[j] = Db[j]; Cr[j] = Cb[j]; }
    __shared__ float sbS[2][8];
    __shared__ float sbL[8];
    int wv = t >> 6;
    float lp = 0.f;
    ushort8 qv = *(const ushort8*)(Lq + (size_t)(chunk * CH_ROWS) * LQ_STRIDE + k0);
    for (int rr = 0; rr < CH_ROWS; ++rr) {
        int r = chunk * CH_ROWS + rr;
        float Lv[8];
#pragma unroll
        for (int j = 0; j < 8; j++) Lv[j] = (float)(short)qv[j] * IQS;
        if (rr < CH_ROWS - 1)
            qv = *(const ushort8*)(Lq + (size_t)(r + 1) * LQ_STRIDE + k0);
        float e[8];
        float dotp = 0.f;
#pragma unroll
        for (int j = 0; j < 8; j++) {
            e[j] = __expf(Lv[j] * (1.0f / TT) + Dr[j]);
            dotp += e[j] * Cr[j];
        }
        dotp = waveReduceSum(dotp);
        int par = rr & 1;
        if ((t & 63) == 0) sbS[par][wv] = dotp;
        __syncthreads();
        float T = 0.f;
#pragma unroll
        for (int q = 0; q < 8; q++) T += sbS[par][q];
        float Rprev = Rv[r];
        float R2 = Rprev / (Rprev * T + SKEPS);
        float ls = lse[r];
        float* row = Lg + (size_t)r * K_;
        f32x4 oa, ob;
#pragma unroll
        for (int j = 0; j < 8; j++) {
            float a = R2 * e[j] * Cr[j];
            lp += a * (Lv[j] * (1.0f / PT) - ls);
            if (j < 4) oa[j] = a; else ob[j - 4] = a;
        }
        *(f32x4*)(row + k0) = oa;
        *(f32x4*)(row + k0 + 4) = ob;
    }
    lp = waveReduceSum(lp);
    if ((t & 63) == 0) sbL[wv] = lp;
    __syncthreads();
    if (t == 0) {
        float tot = 0.f;
        for (int q = 0; q < 8; q++) tot += sbL[q];
        lossp[chunk] = tot;
    }
}

__global__ __launch_bounds__(512) void k_loss(const float* __restrict__ lossp, float* __restrict__ out) {
    int t = threadIdx.x;
    float s = lossp[t];
    s = waveReduceSum(s);
    __shared__ float sb[8];
    if ((t & 63) == 0) sb[t >> 6] = s;
    __syncthreads();
    if (t == 0) {
        float tot = 0.f;
        for (int q = 0; q < 8; q++) tot += sb[q];
        out[LOGITS_ELEMS] = -tot / (float)R_ROWS;
    }
}

extern "C" void kernel_launch(void* const* d_in, const int* in_sizes, int n_in,
                              void* d_out, int out_size, void* d_ws, size_t ws_size,
                              hipStream_t stream) {
    const float* x = (const float*)d_in[0];
    const float* W = (const float*)d_in[1];
    const float* bias = (const float*)d_in[2];
    char* ws = (char*)d_ws;
    __hip_bfloat16* Ap = (__hip_bfloat16*)(ws + OFF_APACK);
    __hip_bfloat16* Bp = (__hip_bfloat16*)(ws + OFF_BPACK);
    float* psum = (float*)(ws + OFF_PSUM);
    float* pmax = (float*)(ws + OFF_PMAX);
    float* psum0 = (float*)(ws + OFF_PSUM0);
    float* Dv = (float*)(ws + OFF_D);
    float* Cc = (float*)(ws + OFF_C);
    float* R = (float*)(ws + OFF_R);
    float* lse = (float*)(ws + OFF_LSE);
    float* lossp = (float*)(ws + OFF_LOSSP);
    float* out = (float*)d_out;
    float* Lg = out;  // int16 logits live row-local inside d_out; passF overwrites with f32

    hipFuncSetAttribute((const void*)k_gemm, hipFuncAttributeMaxDynamicSharedMemorySize, 131072);

    k_pack<<<dim3(R_ROWS + K_), dim3(256), 0, stream>>>(x, W, Ap, Bp);
    k_gemm<<<dim3(K_ / 256, R_ROWS / 256), dim3(512), 131072, stream>>>(Ap, Bp, bias, Lg, pmax, psum0);
    k_prep<<<dim3(128), dim3(256), 0, stream>>>(pmax, psum0, Dv, Cc);
    k_pass<true><<<dim3(NCHUNK), dim3(512), 0, stream>>>(Lg, Dv, Cc, R, psum, lse);
    k_updC<<<dim3(128), dim3(256), 0, stream>>>(psum, Cc);
    k_pass<false><<<dim3(NCHUNK), dim3(512), 0, stream>>>(Lg, Dv, Cc, R, psum, lse);
    k_updC<<<dim3(128), dim3(256), 0, stream>>>(psum, Cc);
    k_passF<<<dim3(NCHUNK), dim3(512), 0, stream>>>(Lg, Dv, Cc, R, lse, lossp);
    k_loss<<<dim3(1), dim3(512), 0, stream>>>(lossp, out);
}